// Round 2
// baseline (287.291 us; speedup 1.0000x reference)
//
#include <hip/hip_runtime.h>
#include <math.h>

// ---------------------------------------------------------------------------
// GCN: h1 = relu(Agg(x@W1)+b1); h2 = relu(Agg(h1@W2)+b2); out = sigmoid(h2@Wfc+bfc)
// Agg(xl)[dst] = dinv[dst] * ( sum_{src->dst} xl_s[src] + xl_s[dst] )
//   where xl_s[n] = (x@W)[n] * dinv[n]   (source-side norm folded into GEMM)
// R2-R9: scan / dinv-fold / counting-sort CSR (no global atomics).
// R10: MFMA GEMMs. R11-R14: node-per-slot gather aggs + fused gemm2.
// R15: 8-way chains -> NULL (VALUBusy/dur unchanged) => not chain-depth-bound.
// R16: EDGE-PARALLEL segmented-reduction aggs. Block owns 64 consecutive
//      nodes + their contiguous CSR edge span (csr now stores (dl<<17)|src).
//      32 slots x 8 octets walk balanced contiguous edge slices: no max-of-8
//      round waste (was ~1.6x), no idx chains (index stream statically known,
//      2-deep pipelined), dst-runs accumulated in registers and flushed to a
//      PAD=65 LDS f32 accumulator via atomicAdd (~1 flush / 17 edges).
//      Layer-1 then adds self row + bias + relu and runs gemm2 on FULL 16-row
//      MFMA A-tiles; layer-2 finishes FC dot + sigmoid in-register.
// ---------------------------------------------------------------------------

typedef __attribute__((ext_vector_type(8))) short bf16x8;
typedef __attribute__((ext_vector_type(4))) float f32x4;
typedef __attribute__((ext_vector_type(2))) float f32x2;

#define CHUNKS 1024

__device__ __forceinline__ unsigned short f2bf(float f) {
    unsigned u = __float_as_uint(f);
    u += 0x7FFFu + ((u >> 16) & 1u);   // round-to-nearest-even
    return (unsigned short)(u >> 16);
}
__device__ __forceinline__ unsigned packbf(float a, float b) {
    return (unsigned)f2bf(a) | ((unsigned)f2bf(b) << 16);
}
// accumulate 8 bf16 (one uint4) into 4 packed f32x2 accumulators
__device__ __forceinline__ void upadd2(uint4 g, f32x2* a) {
    a[0] += (f32x2){__uint_as_float(g.x << 16), __uint_as_float(g.x & 0xFFFF0000u)};
    a[1] += (f32x2){__uint_as_float(g.y << 16), __uint_as_float(g.y & 0xFFFF0000u)};
    a[2] += (f32x2){__uint_as_float(g.z << 16), __uint_as_float(g.z & 0xFFFF0000u)};
    a[3] += (f32x2){__uint_as_float(g.w << 16), __uint_as_float(g.w & 0xFFFF0000u)};
}

// ---- CSR build: bucketed counting sort (no global atomics) ----------------
__global__ __launch_bounds__(256) void k_hist(const int* __restrict__ col, int E,
                                              int NBUK, int CH,
                                              int* __restrict__ hist_g) {
    __shared__ int h[256];
    for (int i = threadIdx.x; i < NBUK; i += 256) h[i] = 0;
    __syncthreads();
    int base = blockIdx.x * CH, hi = min(base + CH, E);
    for (int e = base + (int)threadIdx.x; e < hi; e += 256)
        atomicAdd(&h[col[e] >> 9], 1);
    __syncthreads();
    for (int i = threadIdx.x; i < NBUK; i += 256)
        hist_g[blockIdx.x * NBUK + i] = h[i];
}

__global__ __launch_bounds__(256) void k_colscan(const int* __restrict__ hist_g, int NBUK,
                                                 int* __restrict__ histOff,
                                                 int* __restrict__ bucketTotal) {
    __shared__ int s[256];
    const int b = blockIdx.x, t = threadIdx.x;
    int v[4], sum = 0;
#pragma unroll
    for (int j = 0; j < 4; ++j) {
        v[j] = hist_g[(t * 4 + j) * NBUK + b];
        sum += v[j];
    }
    s[t] = sum;
    __syncthreads();
    for (int off = 1; off < 256; off <<= 1) {
        int u = (t >= off) ? s[t - off] : 0;
        __syncthreads();
        s[t] += u;
        __syncthreads();
    }
    int run = s[t] - sum;
#pragma unroll
    for (int j = 0; j < 4; ++j) {
        histOff[b * CHUNKS + t * 4 + j] = run;
        run += v[j];
    }
    if (t == 255) bucketTotal[b] = run;
}

__global__ __launch_bounds__(256) void k_scan_tot(const int* __restrict__ bucketTotal,
                                                  int NBUK, int E, int N,
                                                  int* __restrict__ bucketBase,
                                                  int* __restrict__ row_off) {
    __shared__ int s[256];
    int t = threadIdx.x;
    int v = (t < NBUK) ? bucketTotal[t] : 0;
    s[t] = v;
    __syncthreads();
    for (int off = 1; off < 256; off <<= 1) {
        int u = (t >= off) ? s[t - off] : 0;
        __syncthreads();
        s[t] += u;
        __syncthreads();
    }
    if (t < NBUK) bucketBase[t] = s[t] - v;
    if (t == 0) row_off[N] = E;
}

__global__ __launch_bounds__(256) void k_scatter(const int* __restrict__ row,
                                                 const int* __restrict__ col, int E,
                                                 int NBUK, int CH,
                                                 const int* __restrict__ bucketBase,
                                                 const int* __restrict__ histOff,
                                                 unsigned* __restrict__ ebuf) {
    __shared__ int cur[256];
    for (int i = threadIdx.x; i < NBUK; i += 256)
        cur[i] = bucketBase[i] + histOff[i * CHUNKS + blockIdx.x];
    __syncthreads();
    int base = blockIdx.x * CH, hi = min(base + CH, E);
    for (int e = base + (int)threadIdx.x; e < hi; e += 256) {
        int d = col[e], src = row[e];
        int b = d >> 9;
        int pos = atomicAdd(&cur[b], 1);             // LDS atomic
        ebuf[pos] = ((unsigned)(d & 511) << 17) | (unsigned)src;
    }
}

__global__ __launch_bounds__(512) void k_bucket(const unsigned* __restrict__ ebuf,
                                                const int* __restrict__ bucketBase,
                                                const int* __restrict__ bucketTotal,
                                                int N,
                                                int* __restrict__ row_off,
                                                float* __restrict__ dinv,
                                                int* __restrict__ csr_src) {
    __shared__ int hc[512], of[512];
    const int bid = blockIdx.x, t = threadIdx.x;
    const int base = bucketBase[bid];
    const int cnt  = bucketTotal[bid];
    hc[t] = 0;
    __syncthreads();
    for (int i = t; i < cnt; i += 512)
        atomicAdd(&hc[ebuf[base + i] >> 17], 1);
    __syncthreads();
    int v = hc[t];
    of[t] = v;
    __syncthreads();
    for (int off = 1; off < 512; off <<= 1) {
        int u = (t >= off) ? of[t - off] : 0;
        __syncthreads();
        of[t] += u;
        __syncthreads();
    }
    int excl = of[t] - v;
    int node = bid * 512 + t;
    if (node < N) {
        row_off[node] = base + excl;
        dinv[node] = rsqrtf((float)(v + 1));   // +1 self loop
    }
    of[t] = excl;
    __syncthreads();
    for (int i = t; i < cnt; i += 512) {
        unsigned e = ebuf[base + i];
        int dl = (int)(e >> 17);
        int pos = atomicAdd(&of[dl], 1);       // LDS atomic
        csr_src[base + pos] = (int)e;          // R16: store packed (dl<<17)|src
    }
}

// ---- MFMA GEMM (layer 1 only) ---------------------------------------------
template <int K, bool BF16IN>
__global__ __launch_bounds__(256) void k_gemm_mfma(const void* __restrict__ xin,
                                                   const float* __restrict__ W,
                                                   const float* __restrict__ dinv,
                                                   unsigned short* __restrict__ out,
                                                   int N) {
    constexpr int KS = K + 8;
    __shared__ short sX[64 * KS];
    __shared__ short sW[64 * KS];
    const int tid = threadIdx.x;
    const int wv = tid >> 6, lane = tid & 63;
    const int q = lane >> 4, m = lane & 15;
    const int nb = blockIdx.x * 64;

    for (int i = tid; i < K * 64; i += 256) {
        int k = i >> 6, c = i & 63;
        sW[c * KS + k] = (short)f2bf(W[i]);
    }
    if (BF16IN) {
        const unsigned short* xb = (const unsigned short*)xin;
        for (int i = tid; i < 64 * (K / 8); i += 256) {
            int r = i / (K / 8), c8 = (i % (K / 8)) * 8;
            int node = nb + r;
            uint4 v = make_uint4(0u, 0u, 0u, 0u);
            if (node < N) v = *(const uint4*)(xb + (size_t)node * K + c8);
            *(uint4*)(&sX[r * KS + c8]) = v;
        }
    } else {
        const float* xf = (const float*)xin;
        for (int i = tid; i < 64 * (K / 8); i += 256) {
            int r = i / (K / 8), c8 = (i % (K / 8)) * 8;
            int node = nb + r;
            uint4 v = make_uint4(0u, 0u, 0u, 0u);
            if (node < N) {
                float4 lo = *(const float4*)(xf + (size_t)node * K + c8);
                float4 hi = *(const float4*)(xf + (size_t)node * K + c8 + 4);
                v.x = packbf(lo.x, lo.y);
                v.y = packbf(lo.z, lo.w);
                v.z = packbf(hi.x, hi.y);
                v.w = packbf(hi.z, hi.w);
            }
            *(uint4*)(&sX[r * KS + c8]) = v;
        }
    }
    __syncthreads();

    f32x4 acc[4] = {};
    const short* aRow = &sX[(wv * 16 + m) * KS + q * 8];
#pragma unroll
    for (int k0 = 0; k0 < K; k0 += 32) {
        bf16x8 a = *(const bf16x8*)(aRow + k0);
#pragma unroll
        for (int ft = 0; ft < 4; ++ft) {
            bf16x8 b = *(const bf16x8*)(&sW[(ft * 16 + m) * KS + k0 + q * 8]);
            acc[ft] = __builtin_amdgcn_mfma_f32_16x16x32_bf16(a, b, acc[ft], 0, 0, 0);
        }
    }
#pragma unroll
    for (int r = 0; r < 4; ++r) {
        int node = nb + wv * 16 + q * 4 + r;
        if (node < N) {
            float di = dinv[node];
#pragma unroll
            for (int ft = 0; ft < 4; ++ft)
                out[(size_t)node * 64 + ft * 16 + m] = f2bf(acc[ft][r] * di);
        }
    }
}

// ---- R16 edge-parallel layer-1 agg + fused gemm2 --------------------------
// Block owns nodes [nb, nb+64) and CSR span [row_off[nb], row_off[nb+64)).
// Slot s (=tid>>3, 32 slots) walks a contiguous balanced slice; octet o
// (=tid&7) owns feats [8o,8o+8). dst-runs accumulate in registers, flush to
// sAcc (PAD=65 f32) via LDS atomicAdd. Phase2: +self row, dinv, bias, relu ->
// bf16 A-tiles (16 full rows/wave). Phase3: 8 MFMA vs LDS W2^T -> xl2.
__global__ __launch_bounds__(256) void k_agg_g2(const unsigned short* __restrict__ xl,
                                                const int* __restrict__ row_off,
                                                const int* __restrict__ csr,
                                                const float* __restrict__ dinv,
                                                const float* __restrict__ bias,
                                                const float* __restrict__ W2,
                                                unsigned short* __restrict__ out, int N) {
    constexpr int PAD = 65;              // f32 stride: odd -> full bank spread
    constexpr int KS = 72;               // bf16 stride for MFMA tiles
    __shared__ float sAcc[64 * PAD];     // 16.6KB
    __shared__ short sH[64 * KS];        // 9.2KB  (4 waves x 16 rows)
    __shared__ short sW2[64 * KS];       // 9.2KB
    const int tid = threadIdx.x;
    const int wv = tid >> 6, lane = tid & 63;
    const int slot = tid >> 3, o = tid & 7;
    const int q = lane >> 4, m = lane & 15;
    const int nb = blockIdx.x * 64;

    // stage W2 transposed bf16: sW2[n*KS+k] = bf16(W2[k*64+n])
    for (int i = tid; i < 64 * 64; i += 256) {
        int k = i >> 6, n = i & 63;
        sW2[n * KS + k] = (short)f2bf(W2[i]);
    }
    // zero accumulators (64*65 = 4160 f32 = 2080 ull)
    for (int i = tid; i < 2080; i += 256)
        ((unsigned long long*)sAcc)[i] = 0ull;
    __syncthreads();

    const int nend = min(nb + 64, N);
    const int beg = row_off[nb];
    const int end = row_off[nend];
    const int blocal = nb & 511;
    const char* xlb = (const char*)xl;
    const unsigned loff = (unsigned)(o << 4);

    // ---- edge phase: contiguous balanced slices, 2-deep pipelined ----
    const int span = end - beg;
    const int len = (span + 31) >> 5;
    int e0 = beg + slot * len;
    int e1 = min(e0 + len, end);
    f32x2 a0[4] = {};
    int cur = -1;
    if (e0 < e1) {
        int pk0 = csr[e0];
        int pk1 = csr[(e0 + 1 < e1) ? e0 + 1 : e1 - 1];
        uint4 G0 = *(const uint4*)(xlb + (((unsigned)(pk0 & 0x1FFFF) << 7) | loff));
        uint4 G1 = *(const uint4*)(xlb + (((unsigned)(pk1 & 0x1FFFF) << 7) | loff));
        for (int e = e0; e < e1; ++e) {
            int pk2 = csr[(e + 2 < e1) ? e + 2 : e1 - 1];
            uint4 G2 = *(const uint4*)(xlb + (((unsigned)(pk2 & 0x1FFFF) << 7) | loff));
            int li = (pk0 >> 17) - blocal;
            if (li != cur) {
                if (cur >= 0) {
                    float* dst = &sAcc[cur * PAD + o * 8];
                    atomicAdd(dst + 0, a0[0].x); atomicAdd(dst + 1, a0[0].y);
                    atomicAdd(dst + 2, a0[1].x); atomicAdd(dst + 3, a0[1].y);
                    atomicAdd(dst + 4, a0[2].x); atomicAdd(dst + 5, a0[2].y);
                    atomicAdd(dst + 6, a0[3].x); atomicAdd(dst + 7, a0[3].y);
                }
                a0[0] = (f32x2){0.f, 0.f}; a0[1] = (f32x2){0.f, 0.f};
                a0[2] = (f32x2){0.f, 0.f}; a0[3] = (f32x2){0.f, 0.f};
                cur = li;
            }
            upadd2(G0, a0);
            pk0 = pk1; pk1 = pk2; G0 = G1; G1 = G2;
        }
        if (cur >= 0) {
            float* dst = &sAcc[cur * PAD + o * 8];
            atomicAdd(dst + 0, a0[0].x); atomicAdd(dst + 1, a0[0].y);
            atomicAdd(dst + 2, a0[1].x); atomicAdd(dst + 3, a0[1].y);
            atomicAdd(dst + 4, a0[2].x); atomicAdd(dst + 5, a0[2].y);
            atomicAdd(dst + 6, a0[3].x); atomicAdd(dst + 7, a0[3].y);
        }
    }
    __syncthreads();

    // ---- phase 2: h1 = relu((acc + self)*dinv + b1) -> bf16 A-tile ----
    for (int i = lane; i < 128; i += 64) {
        int row = i >> 3, oo = i & 7;
        int li = wv * 16 + row;
        int node = nb + li;
        int cn = min(node, N - 1);
        uint4 ow = *(const uint4*)(xl + (size_t)cn * 64 + oo * 8);
        f32x2 own[4] = {};
        upadd2(ow, own);
        float di = dinv[cn];
        const float* ap = &sAcc[li * PAD + oo * 8];
        float4 blo = *(const float4*)(bias + oo * 8);
        float4 bhi = *(const float4*)(bias + oo * 8 + 4);
        float h0 = fmaxf((ap[0] + own[0].x) * di + blo.x, 0.f);
        float h1 = fmaxf((ap[1] + own[0].y) * di + blo.y, 0.f);
        float h2 = fmaxf((ap[2] + own[1].x) * di + blo.z, 0.f);
        float h3 = fmaxf((ap[3] + own[1].y) * di + blo.w, 0.f);
        float h4 = fmaxf((ap[4] + own[2].x) * di + bhi.x, 0.f);
        float h5 = fmaxf((ap[5] + own[2].y) * di + bhi.y, 0.f);
        float h6 = fmaxf((ap[6] + own[3].x) * di + bhi.z, 0.f);
        float h7 = fmaxf((ap[7] + own[3].y) * di + bhi.w, 0.f);
        uint4 hq = make_uint4(0u, 0u, 0u, 0u);
        if (node < N) {
            hq.x = packbf(h0, h1); hq.y = packbf(h2, h3);
            hq.z = packbf(h4, h5); hq.w = packbf(h6, h7);
        }
        *(uint4*)(&sH[li * KS + oo * 8]) = hq;
    }
    __syncthreads();

    // ---- phase 3: gemm2, full 16-row A-tile per wave ----
    f32x4 accm[4] = {};
    const short* aRow = &sH[(wv * 16 + m) * KS + q * 8];
#pragma unroll
    for (int k0 = 0; k0 < 64; k0 += 32) {
        bf16x8 aa = *(const bf16x8*)(aRow + k0);
#pragma unroll
        for (int ft = 0; ft < 4; ++ft) {
            bf16x8 bb = *(const bf16x8*)(&sW2[(ft * 16 + m) * KS + k0 + q * 8]);
            accm[ft] = __builtin_amdgcn_mfma_f32_16x16x32_bf16(aa, bb, accm[ft], 0, 0, 0);
        }
    }
#pragma unroll
    for (int r = 0; r < 4; ++r) {
        int node2 = nb + wv * 16 + q * 4 + r;
        if (node2 < N) {
            float di2 = dinv[node2];
#pragma unroll
            for (int ft = 0; ft < 4; ++ft)
                out[(size_t)node2 * 64 + ft * 16 + m] = f2bf(accm[ft][r] * di2);
        }
    }
}

// ---- R16 edge-parallel layer-2 agg + FC + sigmoid -------------------------
__global__ __launch_bounds__(256) void k_agg_fc(const unsigned short* __restrict__ xl,
                                                const int* __restrict__ row_off,
                                                const int* __restrict__ csr,
                                                const float* __restrict__ dinv,
                                                const float* __restrict__ bias,
                                                const float* __restrict__ Wfc,
                                                const float* __restrict__ bfc,
                                                float* __restrict__ out, int N) {
    constexpr int PAD = 65;
    __shared__ float sAcc[64 * PAD];     // 16.6KB
    const int tid = threadIdx.x;
    const int slot = tid >> 3, o = tid & 7;
    const int nb = blockIdx.x * 64;

    for (int i = tid; i < 2080; i += 256)
        ((unsigned long long*)sAcc)[i] = 0ull;
    __syncthreads();

    const int nend = min(nb + 64, N);
    const int beg = row_off[nb];
    const int end = row_off[nend];
    const int blocal = nb & 511;
    const char* xlb = (const char*)xl;
    const unsigned loff = (unsigned)(o << 4);

    const int span = end - beg;
    const int len = (span + 31) >> 5;
    int e0 = beg + slot * len;
    int e1 = min(e0 + len, end);
    f32x2 a0[4] = {};
    int cur = -1;
    if (e0 < e1) {
        int pk0 = csr[e0];
        int pk1 = csr[(e0 + 1 < e1) ? e0 + 1 : e1 - 1];
        uint4 G0 = *(const uint4*)(xlb + (((unsigned)(pk0 & 0x1FFFF) << 7) | loff));
        uint4 G1 = *(const uint4*)(xlb + (((unsigned)(pk1 & 0x1FFFF) << 7) | loff));
        for (int e = e0; e < e1; ++e) {
            int pk2 = csr[(e + 2 < e1) ? e + 2 : e1 - 1];
            uint4 G2 = *(const uint4*)(xlb + (((unsigned)(pk2 & 0x1FFFF) << 7) | loff));
            int li = (pk0 >> 17) - blocal;
            if (li != cur) {
                if (cur >= 0) {
                    float* dst = &sAcc[cur * PAD + o * 8];
                    atomicAdd(dst + 0, a0[0].x); atomicAdd(dst + 1, a0[0].y);
                    atomicAdd(dst + 2, a0[1].x); atomicAdd(dst + 3, a0[1].y);
                    atomicAdd(dst + 4, a0[2].x); atomicAdd(dst + 5, a0[2].y);
                    atomicAdd(dst + 6, a0[3].x); atomicAdd(dst + 7, a0[3].y);
                }
                a0[0] = (f32x2){0.f, 0.f}; a0[1] = (f32x2){0.f, 0.f};
                a0[2] = (f32x2){0.f, 0.f}; a0[3] = (f32x2){0.f, 0.f};
                cur = li;
            }
            upadd2(G0, a0);
            pk0 = pk1; pk1 = pk2; G0 = G1; G1 = G2;
        }
        if (cur >= 0) {
            float* dst = &sAcc[cur * PAD + o * 8];
            atomicAdd(dst + 0, a0[0].x); atomicAdd(dst + 1, a0[0].y);
            atomicAdd(dst + 2, a0[1].x); atomicAdd(dst + 3, a0[1].y);
            atomicAdd(dst + 4, a0[2].x); atomicAdd(dst + 5, a0[2].y);
            atomicAdd(dst + 6, a0[3].x); atomicAdd(dst + 7, a0[3].y);
        }
    }
    __syncthreads();

    // finish: h2 = relu((acc+self)*dinv + b2); out = sigmoid(h2.Wfc + bfc)
    for (int i = tid; i < 512; i += 256) {
        int row = i >> 3, oo = i & 7;
        int node = nb + row;
        int cn = min(node, N - 1);
        uint4 ow = *(const uint4*)(xl + (size_t)cn * 64 + oo * 8);
        f32x2 own[4] = {};
        upadd2(ow, own);
        float di = dinv[cn];
        const float* ap = &sAcc[row * PAD + oo * 8];
        float4 blo = *(const float4*)(bias + oo * 8);
        float4 bhi = *(const float4*)(bias + oo * 8 + 4);
        float4 wlo = *(const float4*)(Wfc + oo * 8);
        float4 whi = *(const float4*)(Wfc + oo * 8 + 4);
        float v = 0.f;
        v += fmaxf((ap[0] + own[0].x) * di + blo.x, 0.f) * wlo.x;
        v += fmaxf((ap[1] + own[0].y) * di + blo.y, 0.f) * wlo.y;
        v += fmaxf((ap[2] + own[1].x) * di + blo.z, 0.f) * wlo.z;
        v += fmaxf((ap[3] + own[1].y) * di + blo.w, 0.f) * wlo.w;
        v += fmaxf((ap[4] + own[2].x) * di + bhi.x, 0.f) * whi.x;
        v += fmaxf((ap[5] + own[2].y) * di + bhi.y, 0.f) * whi.y;
        v += fmaxf((ap[6] + own[3].x) * di + bhi.z, 0.f) * whi.z;
        v += fmaxf((ap[7] + own[3].y) * di + bhi.w, 0.f) * whi.w;
        v += __shfl_xor(v, 1, 64);
        v += __shfl_xor(v, 2, 64);
        v += __shfl_xor(v, 4, 64);
        if (node < N && oo == 0)
            out[node] = 1.f / (1.f + expf(-(v + bfc[0])));
    }
}

extern "C" void kernel_launch(void* const* d_in, const int* in_sizes, int n_in,
                              void* d_out, int out_size, void* d_ws, size_t ws_size,
                              hipStream_t stream) {
    const float* x   = (const float*)d_in[0];
    const int*   ei  = (const int*)d_in[1];   // [2, E]: row then col
    const float* W1  = (const float*)d_in[2];
    const float* b1  = (const float*)d_in[3];
    const float* W2  = (const float*)d_in[4];
    const float* b2  = (const float*)d_in[5];
    const float* Wfc = (const float*)d_in[6];
    const float* bfc = (const float*)d_in[7];
    float* out = (float*)d_out;

    const int H = in_sizes[3];          // 64
    const int D = in_sizes[2] / H;      // 128
    const int N = in_sizes[0] / D;      // 100000
    const int E = in_sizes[1] / 2;      // 1600000
    const int* row = ei;
    const int* col = ei + E;
    const int NBUK = (N + 511) >> 9;    // 196 buckets of 512 nodes
    const int CH   = (E + CHUNKS - 1) / CHUNKS;

    // Workspace carve-up (256B aligned slices)
    char* p = (char*)d_ws;
    auto carve = [&](size_t bytes) {
        char* r = p;
        p += (bytes + 255) & ~(size_t)255;
        return (void*)r;
    };
    int*            hist_g      = (int*)carve((size_t)CHUNKS * 256 * 4);
    int*            histOff     = (int*)carve((size_t)256 * CHUNKS * 4);
    int*            bucketTotal = (int*)carve((size_t)256 * 4);
    int*            bucketBase  = (int*)carve((size_t)256 * 4);
    unsigned*       ebuf        = (unsigned*)carve((size_t)E * 4);
    int*            csr_src     = (int*)carve((size_t)E * 4);
    int*            row_off     = (int*)carve((size_t)(N + 1) * 4);
    float*          dinv        = (float*)carve((size_t)N * 4);
    unsigned short* bufXL       = (unsigned short*)carve((size_t)N * 64 * 2);
    unsigned short* bufXL2      = (unsigned short*)carve((size_t)N * 64 * 2);
    (void)ws_size;

    const int TB = 256;
    // 1. CSR build (bucketed counting sort; no global atomics)
    k_hist<<<CHUNKS, TB, 0, stream>>>(col, E, NBUK, CH, hist_g);
    k_colscan<<<NBUK, TB, 0, stream>>>(hist_g, NBUK, histOff, bucketTotal);
    k_scan_tot<<<1, TB, 0, stream>>>(bucketTotal, NBUK, E, N, bucketBase, row_off);
    k_scatter<<<CHUNKS, TB, 0, stream>>>(row, col, E, NBUK, CH, bucketBase, histOff, ebuf);
    k_bucket<<<NBUK, 512, 0, stream>>>(ebuf, bucketBase, bucketTotal, N,
                                       row_off, dinv, csr_src);

    int gemmGrid = (N + 63) / 64;       // 1563
    int aggGrid  = (N + 63) / 64;       // 1563 (64 nodes/block, edge-parallel)
    // 2. layer 1 GEMM: xl = bf16((x@W1)*dinv)
    k_gemm_mfma<128, false><<<gemmGrid, TB, 0, stream>>>(x, W1, dinv, bufXL, N);
    // 3. fused layer-1 agg + gemm2: xl2 = bf16(dinv*(relu(dinv*Agg(xl)+b1)@W2))
    k_agg_g2<<<aggGrid, TB, 0, stream>>>(bufXL, row_off, csr_src, dinv, b1, W2, bufXL2, N);
    // 4. layer-2 agg + FC + sigmoid
    k_agg_fc<<<aggGrid, TB, 0, stream>>>(bufXL2, row_off, csr_src, dinv, b2, Wfc, bfc, out, N);
}

// Round 3
// 272.640 us; speedup vs baseline: 1.0537x; 1.0537x over previous
//
#include <hip/hip_runtime.h>
#include <math.h>

// ---------------------------------------------------------------------------
// GCN: h1 = relu(Agg(x@W1)+b1); h2 = relu(Agg(h1@W2)+b2); out = sigmoid(h2@Wfc+bfc)
// Agg(xl)[dst] = dinv[dst] * ( sum_{src->dst} xl_s[src] + xl_s[dst] )
//   where xl_s[n] = (x@W)[n] * dinv[n]   (source-side norm folded into GEMM)
// R2-R9: scan / dinv-fold / counting-sort CSR (no global atomics).
// R10: MFMA GEMMs. R11-R14: node-per-slot gather aggs + fused gemm2 (41.5us).
// R15: 8-way chains -> NULL => not per-wave chain-depth-bound.
// R16: edge-parallel 2-deep -> 76us REGRESSION => aggs are latency x concurrency
//      bound; concurrency saturates at R14's level (4-deep x ~12 waves/CU).
// R17: revert to R14 agg structure (4-deep chains) + DEGREE-BALANCED node
//      permutation (descending counting sort by degree, no global atomics).
//      Waves get 8 near-equal-degree nodes -> mx ~= cnt (was E[max8]~22.7 vs
//      mean 17, 1.34x wasted rounds + wasted fallback gathers). High-degree
//      blocks scheduled first (no slow tail).
// ---------------------------------------------------------------------------

typedef __attribute__((ext_vector_type(8))) short bf16x8;
typedef __attribute__((ext_vector_type(4))) float f32x4;
typedef __attribute__((ext_vector_type(2))) float f32x2;

#define CHUNKS 1024
#define DBINS 256

__device__ __forceinline__ unsigned short f2bf(float f) {
    unsigned u = __float_as_uint(f);
    u += 0x7FFFu + ((u >> 16) & 1u);   // round-to-nearest-even
    return (unsigned short)(u >> 16);
}
__device__ __forceinline__ unsigned packbf(float a, float b) {
    return (unsigned)f2bf(a) | ((unsigned)f2bf(b) << 16);
}
// accumulate 8 bf16 (one uint4) into 4 packed f32x2 accumulators
__device__ __forceinline__ void upadd2(uint4 g, f32x2* a) {
    a[0] += (f32x2){__uint_as_float(g.x << 16), __uint_as_float(g.x & 0xFFFF0000u)};
    a[1] += (f32x2){__uint_as_float(g.y << 16), __uint_as_float(g.y & 0xFFFF0000u)};
    a[2] += (f32x2){__uint_as_float(g.z << 16), __uint_as_float(g.z & 0xFFFF0000u)};
    a[3] += (f32x2){__uint_as_float(g.w << 16), __uint_as_float(g.w & 0xFFFF0000u)};
}

// ---- CSR build: bucketed counting sort (no global atomics) ----------------
__global__ __launch_bounds__(256) void k_hist(const int* __restrict__ col, int E,
                                              int NBUK, int CH,
                                              int* __restrict__ hist_g) {
    __shared__ int h[256];
    for (int i = threadIdx.x; i < NBUK; i += 256) h[i] = 0;
    __syncthreads();
    int base = blockIdx.x * CH, hi = min(base + CH, E);
    for (int e = base + (int)threadIdx.x; e < hi; e += 256)
        atomicAdd(&h[col[e] >> 9], 1);
    __syncthreads();
    for (int i = threadIdx.x; i < NBUK; i += 256)
        hist_g[blockIdx.x * NBUK + i] = h[i];
}

__global__ __launch_bounds__(256) void k_colscan(const int* __restrict__ hist_g, int NBUK,
                                                 int* __restrict__ histOff,
                                                 int* __restrict__ bucketTotal) {
    __shared__ int s[256];
    const int b = blockIdx.x, t = threadIdx.x;
    int v[4], sum = 0;
#pragma unroll
    for (int j = 0; j < 4; ++j) {
        v[j] = hist_g[(t * 4 + j) * NBUK + b];
        sum += v[j];
    }
    s[t] = sum;
    __syncthreads();
    for (int off = 1; off < 256; off <<= 1) {
        int u = (t >= off) ? s[t - off] : 0;
        __syncthreads();
        s[t] += u;
        __syncthreads();
    }
    int run = s[t] - sum;
#pragma unroll
    for (int j = 0; j < 4; ++j) {
        histOff[b * CHUNKS + t * 4 + j] = run;
        run += v[j];
    }
    if (t == 255) bucketTotal[b] = run;
}

__global__ __launch_bounds__(256) void k_scan_tot(const int* __restrict__ bucketTotal,
                                                  int NBUK, int E, int N,
                                                  int* __restrict__ bucketBase,
                                                  int* __restrict__ row_off) {
    __shared__ int s[256];
    int t = threadIdx.x;
    int v = (t < NBUK) ? bucketTotal[t] : 0;
    s[t] = v;
    __syncthreads();
    for (int off = 1; off < 256; off <<= 1) {
        int u = (t >= off) ? s[t - off] : 0;
        __syncthreads();
        s[t] += u;
        __syncthreads();
    }
    if (t < NBUK) bucketBase[t] = s[t] - v;
    if (t == 0) row_off[N] = E;
}

__global__ __launch_bounds__(256) void k_scatter(const int* __restrict__ row,
                                                 const int* __restrict__ col, int E,
                                                 int NBUK, int CH,
                                                 const int* __restrict__ bucketBase,
                                                 const int* __restrict__ histOff,
                                                 unsigned* __restrict__ ebuf) {
    __shared__ int cur[256];
    for (int i = threadIdx.x; i < NBUK; i += 256)
        cur[i] = bucketBase[i] + histOff[i * CHUNKS + blockIdx.x];
    __syncthreads();
    int base = blockIdx.x * CH, hi = min(base + CH, E);
    for (int e = base + (int)threadIdx.x; e < hi; e += 256) {
        int d = col[e], src = row[e];
        int b = d >> 9;
        int pos = atomicAdd(&cur[b], 1);             // LDS atomic
        ebuf[pos] = ((unsigned)(d & 511) << 17) | (unsigned)src;
    }
}

__global__ __launch_bounds__(512) void k_bucket(const unsigned* __restrict__ ebuf,
                                                const int* __restrict__ bucketBase,
                                                const int* __restrict__ bucketTotal,
                                                int N,
                                                int* __restrict__ row_off,
                                                float* __restrict__ dinv,
                                                int* __restrict__ csr_src) {
    __shared__ int hc[512], of[512];
    const int bid = blockIdx.x, t = threadIdx.x;
    const int base = bucketBase[bid];
    const int cnt  = bucketTotal[bid];
    hc[t] = 0;
    __syncthreads();
    for (int i = t; i < cnt; i += 512)
        atomicAdd(&hc[ebuf[base + i] >> 17], 1);
    __syncthreads();
    int v = hc[t];
    of[t] = v;
    __syncthreads();
    for (int off = 1; off < 512; off <<= 1) {
        int u = (t >= off) ? of[t - off] : 0;
        __syncthreads();
        of[t] += u;
        __syncthreads();
    }
    int excl = of[t] - v;
    int node = bid * 512 + t;
    if (node < N) {
        row_off[node] = base + excl;
        dinv[node] = rsqrtf((float)(v + 1));   // +1 self loop
    }
    of[t] = excl;
    __syncthreads();
    for (int i = t; i < cnt; i += 512) {
        unsigned e = ebuf[base + i];
        int dl = (int)(e >> 17), src = (int)(e & 0x1FFFFu);
        int pos = atomicAdd(&of[dl], 1);       // LDS atomic
        csr_src[base + pos] = src;
    }
}

// ---- R17: degree-balanced permutation (descending counting sort) ----------
__global__ __launch_bounds__(256) void k_deg_hist(const int* __restrict__ row_off, int N,
                                                  int* __restrict__ dhist) {
    __shared__ int h[DBINS];
    for (int i = threadIdx.x; i < DBINS; i += 256) h[i] = 0;
    __syncthreads();
    int base = blockIdx.x * 512, lim = min(base + 512, N);
    for (int i = base + (int)threadIdx.x; i < lim; i += 256) {
        int deg = row_off[i + 1] - row_off[i];
        int bin = 255 - min(deg, 255);        // descending degree
        atomicAdd(&h[bin], 1);
    }
    __syncthreads();
    for (int i = threadIdx.x; i < DBINS; i += 256)
        dhist[blockIdx.x * DBINS + i] = h[i];
}

__global__ __launch_bounds__(256) void k_deg_scan(const int* __restrict__ dhist, int NB,
                                                  int* __restrict__ dOff) {
    __shared__ int s[256];
    const int b = threadIdx.x;
    int tot = 0;
    for (int c = 0; c < NB; ++c) tot += dhist[c * DBINS + b];
    s[b] = tot;
    __syncthreads();
    for (int off = 1; off < 256; off <<= 1) {
        int u = (b >= off) ? s[b - off] : 0;
        __syncthreads();
        s[b] += u;
        __syncthreads();
    }
    int run = s[b] - tot;                     // exclusive bin start
    for (int c = 0; c < NB; ++c) {
        dOff[c * DBINS + b] = run;
        run += dhist[c * DBINS + b];
    }
}

__global__ __launch_bounds__(256) void k_deg_scatter(const int* __restrict__ row_off, int N,
                                                     const int* __restrict__ dOff,
                                                     int* __restrict__ perm) {
    __shared__ int cur[DBINS];
    for (int i = threadIdx.x; i < DBINS; i += 256)
        cur[i] = dOff[blockIdx.x * DBINS + i];
    __syncthreads();
    int base = blockIdx.x * 512, lim = min(base + 512, N);
    for (int i = base + (int)threadIdx.x; i < lim; i += 256) {
        int deg = row_off[i + 1] - row_off[i];
        int bin = 255 - min(deg, 255);
        int pos = atomicAdd(&cur[bin], 1);    // LDS atomic
        perm[pos] = i;
    }
}

// ---- MFMA GEMM (layer 1 only) ---------------------------------------------
template <int K, bool BF16IN>
__global__ __launch_bounds__(256) void k_gemm_mfma(const void* __restrict__ xin,
                                                   const float* __restrict__ W,
                                                   const float* __restrict__ dinv,
                                                   unsigned short* __restrict__ out,
                                                   int N) {
    constexpr int KS = K + 8;
    __shared__ short sX[64 * KS];
    __shared__ short sW[64 * KS];
    const int tid = threadIdx.x;
    const int wv = tid >> 6, lane = tid & 63;
    const int q = lane >> 4, m = lane & 15;
    const int nb = blockIdx.x * 64;

    for (int i = tid; i < K * 64; i += 256) {
        int k = i >> 6, c = i & 63;
        sW[c * KS + k] = (short)f2bf(W[i]);
    }
    if (BF16IN) {
        const unsigned short* xb = (const unsigned short*)xin;
        for (int i = tid; i < 64 * (K / 8); i += 256) {
            int r = i / (K / 8), c8 = (i % (K / 8)) * 8;
            int node = nb + r;
            uint4 v = make_uint4(0u, 0u, 0u, 0u);
            if (node < N) v = *(const uint4*)(xb + (size_t)node * K + c8);
            *(uint4*)(&sX[r * KS + c8]) = v;
        }
    } else {
        const float* xf = (const float*)xin;
        for (int i = tid; i < 64 * (K / 8); i += 256) {
            int r = i / (K / 8), c8 = (i % (K / 8)) * 8;
            int node = nb + r;
            uint4 v = make_uint4(0u, 0u, 0u, 0u);
            if (node < N) {
                float4 lo = *(const float4*)(xf + (size_t)node * K + c8);
                float4 hi = *(const float4*)(xf + (size_t)node * K + c8 + 4);
                v.x = packbf(lo.x, lo.y);
                v.y = packbf(lo.z, lo.w);
                v.z = packbf(hi.x, hi.y);
                v.w = packbf(hi.z, hi.w);
            }
            *(uint4*)(&sX[r * KS + c8]) = v;
        }
    }
    __syncthreads();

    f32x4 acc[4] = {};
    const short* aRow = &sX[(wv * 16 + m) * KS + q * 8];
#pragma unroll
    for (int k0 = 0; k0 < K; k0 += 32) {
        bf16x8 a = *(const bf16x8*)(aRow + k0);
#pragma unroll
        for (int ft = 0; ft < 4; ++ft) {
            bf16x8 b = *(const bf16x8*)(&sW[(ft * 16 + m) * KS + k0 + q * 8]);
            acc[ft] = __builtin_amdgcn_mfma_f32_16x16x32_bf16(a, b, acc[ft], 0, 0, 0);
        }
    }
#pragma unroll
    for (int r = 0; r < 4; ++r) {
        int node = nb + wv * 16 + q * 4 + r;
        if (node < N) {
            float di = dinv[node];
#pragma unroll
            for (int ft = 0; ft < 4; ++ft)
                out[(size_t)node * 64 + ft * 16 + m] = f2bf(acc[ft][r] * di);
        }
    }
}

// ---- fused layer-1 agg + gemm2 (R14 structure + perm) ---------------------
// Phase A (gather): 8 nodes/wave via perm (degree-balanced), slot s=lane>>3
// owns node, octet o=lane&7 owns feats [8o,8o+8); 4-way prefetched chains.
// Phase B (gemm2): wave writes its 8 h1 rows (bf16) into a private LDS
// A-tile (rows 8-15 zero), 8 mfma_16x16x32_bf16 vs LDS W2^T, dinv -> xl2.
__global__ __launch_bounds__(256) void k_agg_g2(const unsigned short* __restrict__ xl,
                                                const int* __restrict__ row_off,
                                                const int* __restrict__ csr_src,
                                                const float* __restrict__ dinv,
                                                const float* __restrict__ bias,
                                                const float* __restrict__ W2,
                                                const int* __restrict__ perm,
                                                unsigned short* __restrict__ out, int N) {
    constexpr int KS = 72;               // 64 + 8 pad (bf16 elems)
    __shared__ short sH[4 * 16 * KS];    // per-wave 16x64 A-tiles (9KB)
    __shared__ short sW2[64 * KS];       // W2^T bf16 (9KB)
    const int tid = threadIdx.x;
    const int wv = tid >> 6, lane = tid & 63;
    const int s = lane >> 3, o = lane & 7;
    const int q = lane >> 4, m = lane & 15;

    // stage W2 transposed bf16: sW2[n*KS+k] = bf16(W2[k*64+n])
    for (int i = tid; i < 64 * 64; i += 256) {
        int k = i >> 6, n = i & 63;
        sW2[n * KS + k] = (short)f2bf(W2[i]);
    }
    // zero this wave's A-tile rows 8-15 (never written by gather phase)
    short* myH = &sH[wv * 16 * KS];
    for (int i = lane; i < 8 * KS / 4; i += 64)
        ((unsigned long long*)(myH + 8 * KS))[i] = 0ull;
    __syncthreads();                     // sW2 visible to all waves

    const int base8 = (blockIdx.x * 4 + wv) * 8;
    const int gi = base8 + s;
    const bool active = gi < N;
    const int node = perm[min(gi, N - 1)];
    const int beg = row_off[node];
    const int deg = row_off[node + 1] - beg;
    const int cnt = active ? deg + 1 : 0;
    int mx = cnt;
    mx = max(mx, __shfl_xor(mx, 8, 64));
    mx = max(mx, __shfl_xor(mx, 16, 64));
    mx = max(mx, __shfl_xor(mx, 32, 64));
    const char* xlb = (const char*)xl;
    const unsigned loff = (unsigned)(o << 4);
    f32x2 acc0[4] = {}, acc1[4] = {};
    int idx[4];
#pragma unroll
    for (int j = 0; j < 4; ++j) idx[j] = (j < deg) ? csr_src[beg + j] : node;
    for (int it = 0; it < mx; it += 4) {
        int c[4];
        bool v[4];
#pragma unroll
        for (int j = 0; j < 4; ++j) {
            c[j] = idx[j];
            v[j] = (it + j) < cnt;
            idx[j] = (it + 4 + j < deg) ? csr_src[beg + it + 4 + j] : node;
        }
        uint4 g0 = *(const uint4*)(xlb + (((unsigned)c[0] << 7) | loff));
        uint4 g1 = *(const uint4*)(xlb + (((unsigned)c[1] << 7) | loff));
        uint4 g2 = *(const uint4*)(xlb + (((unsigned)c[2] << 7) | loff));
        uint4 g3 = *(const uint4*)(xlb + (((unsigned)c[3] << 7) | loff));
        if (!v[0]) g0 = make_uint4(0u, 0u, 0u, 0u);
        if (!v[1]) g1 = make_uint4(0u, 0u, 0u, 0u);
        if (!v[2]) g2 = make_uint4(0u, 0u, 0u, 0u);
        if (!v[3]) g3 = make_uint4(0u, 0u, 0u, 0u);
        upadd2(g0, acc0);
        upadd2(g1, acc1);
        upadd2(g2, acc0);
        upadd2(g3, acc1);
    }
#pragma unroll
    for (int j = 0; j < 4; ++j) acc0[j] += acc1[j];
    // h1 row -> LDS A-tile (bf16), row = slot s
    {
        float di = dinv[node];
        float4 blo = *(const float4*)(bias + o * 8);
        float4 bhi = *(const float4*)(bias + o * 8 + 4);
        uint4 h;
        h.x = packbf(fmaxf(acc0[0].x * di + blo.x, 0.f), fmaxf(acc0[0].y * di + blo.y, 0.f));
        h.y = packbf(fmaxf(acc0[1].x * di + blo.z, 0.f), fmaxf(acc0[1].y * di + blo.w, 0.f));
        h.z = packbf(fmaxf(acc0[2].x * di + bhi.x, 0.f), fmaxf(acc0[2].y * di + bhi.y, 0.f));
        h.w = packbf(fmaxf(acc0[3].x * di + bhi.z, 0.f), fmaxf(acc0[3].y * di + bhi.w, 0.f));
        *(uint4*)(myH + s * KS + o * 8) = h;     // same-wave LDS, no barrier
    }
    // gemm2: 8 MFMA (4 feat-tiles x K=64)
    f32x4 accm[4] = {};
#pragma unroll
    for (int k0 = 0; k0 < 64; k0 += 32) {
        bf16x8 a = *(const bf16x8*)(myH + m * KS + q * 8 + k0);
#pragma unroll
        for (int ft = 0; ft < 4; ++ft) {
            bf16x8 b = *(const bf16x8*)(&sW2[(ft * 16 + m) * KS + k0 + q * 8]);
            accm[ft] = __builtin_amdgcn_mfma_f32_16x16x32_bf16(a, b, accm[ft], 0, 0, 0);
        }
    }
    if (q < 2) {                          // valid rows 0..7
#pragma unroll
        for (int r = 0; r < 4; ++r) {
            int gi2 = base8 + q * 4 + r;
            if (gi2 < N) {
                int node2 = perm[gi2];
                float di2 = dinv[node2];
#pragma unroll
                for (int ft = 0; ft < 4; ++ft)
                    out[(size_t)node2 * 64 + ft * 16 + m] = f2bf(accm[ft][r] * di2);
            }
        }
    }
}

// Layer-2 agg + final FC + sigmoid (4-way chains + perm; octet fold shfl).
__global__ __launch_bounds__(256) void k_agg_fc(const unsigned short* __restrict__ xl,
                                                const int* __restrict__ row_off,
                                                const int* __restrict__ csr_src,
                                                const float* __restrict__ dinv,
                                                const float* __restrict__ bias,
                                                const float* __restrict__ Wfc,
                                                const float* __restrict__ bfc,
                                                const int* __restrict__ perm,
                                                float* __restrict__ out, int N) {
    const int wave = threadIdx.x >> 6, lane = threadIdx.x & 63;
    const int s = lane >> 3, o = lane & 7;
    const int gi = (blockIdx.x * 4 + wave) * 8 + s;
    const bool active = gi < N;
    const int node = perm[min(gi, N - 1)];
    const int beg = row_off[node];
    const int deg = row_off[node + 1] - beg;
    const int cnt = active ? deg + 1 : 0;
    int mx = cnt;
    mx = max(mx, __shfl_xor(mx, 8, 64));
    mx = max(mx, __shfl_xor(mx, 16, 64));
    mx = max(mx, __shfl_xor(mx, 32, 64));
    const char* xlb = (const char*)xl;
    const unsigned loff = (unsigned)(o << 4);
    f32x2 acc0[4] = {}, acc1[4] = {};
    int idx[4];
#pragma unroll
    for (int j = 0; j < 4; ++j) idx[j] = (j < deg) ? csr_src[beg + j] : node;
    for (int it = 0; it < mx; it += 4) {
        int c[4];
        bool v[4];
#pragma unroll
        for (int j = 0; j < 4; ++j) {
            c[j] = idx[j];
            v[j] = (it + j) < cnt;
            idx[j] = (it + 4 + j < deg) ? csr_src[beg + it + 4 + j] : node;
        }
        uint4 g0 = *(const uint4*)(xlb + (((unsigned)c[0] << 7) | loff));
        uint4 g1 = *(const uint4*)(xlb + (((unsigned)c[1] << 7) | loff));
        uint4 g2 = *(const uint4*)(xlb + (((unsigned)c[2] << 7) | loff));
        uint4 g3 = *(const uint4*)(xlb + (((unsigned)c[3] << 7) | loff));
        if (!v[0]) g0 = make_uint4(0u, 0u, 0u, 0u);
        if (!v[1]) g1 = make_uint4(0u, 0u, 0u, 0u);
        if (!v[2]) g2 = make_uint4(0u, 0u, 0u, 0u);
        if (!v[3]) g3 = make_uint4(0u, 0u, 0u, 0u);
        upadd2(g0, acc0);
        upadd2(g1, acc1);
        upadd2(g2, acc0);
        upadd2(g3, acc1);
    }
#pragma unroll
    for (int j = 0; j < 4; ++j) acc0[j] += acc1[j];
    const float di = dinv[node];
    float4 blo = *(const float4*)(bias + o * 8);
    float4 bhi = *(const float4*)(bias + o * 8 + 4);
    float4 wlo = *(const float4*)(Wfc + o * 8);
    float4 whi = *(const float4*)(Wfc + o * 8 + 4);
    float v = 0.f;
    v += fmaxf(acc0[0].x * di + blo.x, 0.f) * wlo.x;
    v += fmaxf(acc0[0].y * di + blo.y, 0.f) * wlo.y;
    v += fmaxf(acc0[1].x * di + blo.z, 0.f) * wlo.z;
    v += fmaxf(acc0[1].y * di + blo.w, 0.f) * wlo.w;
    v += fmaxf(acc0[2].x * di + bhi.x, 0.f) * whi.x;
    v += fmaxf(acc0[2].y * di + bhi.y, 0.f) * whi.y;
    v += fmaxf(acc0[3].x * di + bhi.z, 0.f) * whi.z;
    v += fmaxf(acc0[3].y * di + bhi.w, 0.f) * whi.w;
    v += __shfl_xor(v, 1, 64);
    v += __shfl_xor(v, 2, 64);
    v += __shfl_xor(v, 4, 64);
    if (active && o == 0) out[node] = 1.f / (1.f + expf(-(v + bfc[0])));
}

extern "C" void kernel_launch(void* const* d_in, const int* in_sizes, int n_in,
                              void* d_out, int out_size, void* d_ws, size_t ws_size,
                              hipStream_t stream) {
    const float* x   = (const float*)d_in[0];
    const int*   ei  = (const int*)d_in[1];   // [2, E]: row then col
    const float* W1  = (const float*)d_in[2];
    const float* b1  = (const float*)d_in[3];
    const float* W2  = (const float*)d_in[4];
    const float* b2  = (const float*)d_in[5];
    const float* Wfc = (const float*)d_in[6];
    const float* bfc = (const float*)d_in[7];
    float* out = (float*)d_out;

    const int H = in_sizes[3];          // 64
    const int D = in_sizes[2] / H;      // 128
    const int N = in_sizes[0] / D;      // 100000
    const int E = in_sizes[1] / 2;      // 1600000
    const int* row = ei;
    const int* col = ei + E;
    const int NBUK = (N + 511) >> 9;    // 196 buckets of 512 nodes
    const int CH   = (E + CHUNKS - 1) / CHUNKS;

    // Workspace carve-up (256B aligned slices)
    char* p = (char*)d_ws;
    auto carve = [&](size_t bytes) {
        char* r = p;
        p += (bytes + 255) & ~(size_t)255;
        return (void*)r;
    };
    int*            hist_g      = (int*)carve((size_t)CHUNKS * 256 * 4);
    int*            histOff     = (int*)carve((size_t)256 * CHUNKS * 4);
    int*            bucketTotal = (int*)carve((size_t)256 * 4);
    int*            bucketBase  = (int*)carve((size_t)256 * 4);
    unsigned*       ebuf        = (unsigned*)carve((size_t)E * 4);
    int*            csr_src     = (int*)carve((size_t)E * 4);
    int*            row_off     = (int*)carve((size_t)(N + 1) * 4);
    float*          dinv        = (float*)carve((size_t)N * 4);
    int*            perm        = (int*)carve((size_t)N * 4);
    int*            dhist       = (int*)carve((size_t)NBUK * DBINS * 4);
    int*            dOff        = (int*)carve((size_t)NBUK * DBINS * 4);
    unsigned short* bufXL       = (unsigned short*)carve((size_t)N * 64 * 2);
    unsigned short* bufXL2      = (unsigned short*)carve((size_t)N * 64 * 2);
    (void)ws_size;

    const int TB = 256;
    // 1. CSR build (bucketed counting sort; no global atomics)
    k_hist<<<CHUNKS, TB, 0, stream>>>(col, E, NBUK, CH, hist_g);
    k_colscan<<<NBUK, TB, 0, stream>>>(hist_g, NBUK, histOff, bucketTotal);
    k_scan_tot<<<1, TB, 0, stream>>>(bucketTotal, NBUK, E, N, bucketBase, row_off);
    k_scatter<<<CHUNKS, TB, 0, stream>>>(row, col, E, NBUK, CH, bucketBase, histOff, ebuf);
    k_bucket<<<NBUK, 512, 0, stream>>>(ebuf, bucketBase, bucketTotal, N,
                                       row_off, dinv, csr_src);
    // 1b. degree-balanced permutation (descending)
    k_deg_hist<<<NBUK, TB, 0, stream>>>(row_off, N, dhist);
    k_deg_scan<<<1, TB, 0, stream>>>(dhist, NBUK, dOff);
    k_deg_scatter<<<NBUK, TB, 0, stream>>>(row_off, N, dOff, perm);

    int gemmGrid = (N + 63) / 64;       // 1563
    int aggGrid  = (N + 31) / 32;       // 3125 (8 nodes/wave x 4 waves)
    // 2. layer 1 GEMM: xl = bf16((x@W1)*dinv)
    k_gemm_mfma<128, false><<<gemmGrid, TB, 0, stream>>>(x, W1, dinv, bufXL, N);
    // 3. fused layer-1 agg + gemm2: xl2 = bf16(dinv*(relu(dinv*Agg(xl)+b1)@W2))
    k_agg_g2<<<aggGrid, TB, 0, stream>>>(bufXL, row_off, csr_src, dinv, b1, W2, perm, bufXL2, N);
    // 4. layer-2 agg + FC + sigmoid
    k_agg_fc<<<aggGrid, TB, 0, stream>>>(bufXL2, row_off, csr_src, dinv, b2, Wfc, bfc, perm, out, N);
}

// Round 4
// 263.600 us; speedup vs baseline: 1.0899x; 1.0343x over previous
//
#include <hip/hip_runtime.h>
#include <math.h>

// ---------------------------------------------------------------------------
// GCN: h1 = relu(Agg(x@W1)+b1); h2 = relu(Agg(h1@W2)+b2); out = sigmoid(h2@Wfc+bfc)
// Agg(xl)[dst] = dinv[dst] * ( sum_{src->dst} xl_s[src] + xl_s[dst] )
//   where xl_s[n] = (x@W)[n] * dinv[n]   (source-side norm folded into GEMM)
// R2-R9: scan / dinv-fold / counting-sort CSR (no global atomics).
// R10: MFMA GEMMs. R11-R14: node-per-slot gather aggs + fused gemm2 (41.5us).
// R15: 8-way chains -> NULL => not per-wave chain-depth-bound.
// R16: edge-parallel 2-deep -> 76us REGRESSION => concurrency saturates.
// R17: degree-balanced perm -> agg NULL + 49us serial scan kernel REGRESSION.
//      Conclusion: random-gather path past L2 is queueing-limited (FETCH 83MB
//      of 218MB requested crosses fabric at ~2TB/s; offered concurrency is
//      refused). => shrink the working set, not the depth.
// R18: drop perm; SORT each adjacency list ascending by src (k_sortadj, LDS
//      insertion sort per bucket, one-time ~5us). Aggs walk lists in order,
//      so at round k all waves read srcs near quantile k/deg -> moving ~3-4MB
//      window fits per-XCD L2 -> L2-miss/fabric queueing drops.
// ---------------------------------------------------------------------------

typedef __attribute__((ext_vector_type(8))) short bf16x8;
typedef __attribute__((ext_vector_type(4))) float f32x4;
typedef __attribute__((ext_vector_type(2))) float f32x2;

#define CHUNKS 1024

__device__ __forceinline__ unsigned short f2bf(float f) {
    unsigned u = __float_as_uint(f);
    u += 0x7FFFu + ((u >> 16) & 1u);   // round-to-nearest-even
    return (unsigned short)(u >> 16);
}
__device__ __forceinline__ unsigned packbf(float a, float b) {
    return (unsigned)f2bf(a) | ((unsigned)f2bf(b) << 16);
}
// accumulate 8 bf16 (one uint4) into 4 packed f32x2 accumulators
__device__ __forceinline__ void upadd2(uint4 g, f32x2* a) {
    a[0] += (f32x2){__uint_as_float(g.x << 16), __uint_as_float(g.x & 0xFFFF0000u)};
    a[1] += (f32x2){__uint_as_float(g.y << 16), __uint_as_float(g.y & 0xFFFF0000u)};
    a[2] += (f32x2){__uint_as_float(g.z << 16), __uint_as_float(g.z & 0xFFFF0000u)};
    a[3] += (f32x2){__uint_as_float(g.w << 16), __uint_as_float(g.w & 0xFFFF0000u)};
}

// ---- CSR build: bucketed counting sort (no global atomics) ----------------
__global__ __launch_bounds__(256) void k_hist(const int* __restrict__ col, int E,
                                              int NBUK, int CH,
                                              int* __restrict__ hist_g) {
    __shared__ int h[256];
    for (int i = threadIdx.x; i < NBUK; i += 256) h[i] = 0;
    __syncthreads();
    int base = blockIdx.x * CH, hi = min(base + CH, E);
    for (int e = base + (int)threadIdx.x; e < hi; e += 256)
        atomicAdd(&h[col[e] >> 9], 1);
    __syncthreads();
    for (int i = threadIdx.x; i < NBUK; i += 256)
        hist_g[blockIdx.x * NBUK + i] = h[i];
}

__global__ __launch_bounds__(256) void k_colscan(const int* __restrict__ hist_g, int NBUK,
                                                 int* __restrict__ histOff,
                                                 int* __restrict__ bucketTotal) {
    __shared__ int s[256];
    const int b = blockIdx.x, t = threadIdx.x;
    int v[4], sum = 0;
#pragma unroll
    for (int j = 0; j < 4; ++j) {
        v[j] = hist_g[(t * 4 + j) * NBUK + b];
        sum += v[j];
    }
    s[t] = sum;
    __syncthreads();
    for (int off = 1; off < 256; off <<= 1) {
        int u = (t >= off) ? s[t - off] : 0;
        __syncthreads();
        s[t] += u;
        __syncthreads();
    }
    int run = s[t] - sum;
#pragma unroll
    for (int j = 0; j < 4; ++j) {
        histOff[b * CHUNKS + t * 4 + j] = run;
        run += v[j];
    }
    if (t == 255) bucketTotal[b] = run;
}

__global__ __launch_bounds__(256) void k_scan_tot(const int* __restrict__ bucketTotal,
                                                  int NBUK, int E, int N,
                                                  int* __restrict__ bucketBase,
                                                  int* __restrict__ row_off) {
    __shared__ int s[256];
    int t = threadIdx.x;
    int v = (t < NBUK) ? bucketTotal[t] : 0;
    s[t] = v;
    __syncthreads();
    for (int off = 1; off < 256; off <<= 1) {
        int u = (t >= off) ? s[t - off] : 0;
        __syncthreads();
        s[t] += u;
        __syncthreads();
    }
    if (t < NBUK) bucketBase[t] = s[t] - v;
    if (t == 0) row_off[N] = E;
}

__global__ __launch_bounds__(256) void k_scatter(const int* __restrict__ row,
                                                 const int* __restrict__ col, int E,
                                                 int NBUK, int CH,
                                                 const int* __restrict__ bucketBase,
                                                 const int* __restrict__ histOff,
                                                 unsigned* __restrict__ ebuf) {
    __shared__ int cur[256];
    for (int i = threadIdx.x; i < NBUK; i += 256)
        cur[i] = bucketBase[i] + histOff[i * CHUNKS + blockIdx.x];
    __syncthreads();
    int base = blockIdx.x * CH, hi = min(base + CH, E);
    for (int e = base + (int)threadIdx.x; e < hi; e += 256) {
        int d = col[e], src = row[e];
        int b = d >> 9;
        int pos = atomicAdd(&cur[b], 1);             // LDS atomic
        ebuf[pos] = ((unsigned)(d & 511) << 17) | (unsigned)src;
    }
}

__global__ __launch_bounds__(512) void k_bucket(const unsigned* __restrict__ ebuf,
                                                const int* __restrict__ bucketBase,
                                                const int* __restrict__ bucketTotal,
                                                int N,
                                                int* __restrict__ row_off,
                                                float* __restrict__ dinv,
                                                int* __restrict__ csr_src) {
    __shared__ int hc[512], of[512];
    const int bid = blockIdx.x, t = threadIdx.x;
    const int base = bucketBase[bid];
    const int cnt  = bucketTotal[bid];
    hc[t] = 0;
    __syncthreads();
    for (int i = t; i < cnt; i += 512)
        atomicAdd(&hc[ebuf[base + i] >> 17], 1);
    __syncthreads();
    int v = hc[t];
    of[t] = v;
    __syncthreads();
    for (int off = 1; off < 512; off <<= 1) {
        int u = (t >= off) ? of[t - off] : 0;
        __syncthreads();
        of[t] += u;
        __syncthreads();
    }
    int excl = of[t] - v;
    int node = bid * 512 + t;
    if (node < N) {
        row_off[node] = base + excl;
        dinv[node] = rsqrtf((float)(v + 1));   // +1 self loop
    }
    of[t] = excl;
    __syncthreads();
    for (int i = t; i < cnt; i += 512) {
        unsigned e = ebuf[base + i];
        int dl = (int)(e >> 17), src = (int)(e & 0x1FFFFu);
        int pos = atomicAdd(&of[dl], 1);       // LDS atomic
        csr_src[base + pos] = src;
    }
}

// ---- R18: sort each adjacency list ascending by src (in-LDS) --------------
// One block per 512-node bucket: cooperative load of the bucket's edge span
// into LDS, per-thread insertion sort of its own dst segment, coop store.
__global__ __launch_bounds__(512) void k_sortadj(const int* __restrict__ row_off,
                                                 const int* __restrict__ bucketBase,
                                                 const int* __restrict__ bucketTotal,
                                                 int N,
                                                 int* __restrict__ csr_src) {
    __shared__ int sE[10240];            // 40KB; bucket cnt ~8.2k avg, <<10240
    const int bid = blockIdx.x, t = threadIdx.x;
    const int base = bucketBase[bid];
    const int cnt  = bucketTotal[bid];
    for (int i = t; i < cnt; i += 512) sE[i] = csr_src[base + i];
    __syncthreads();
    int node = bid * 512 + t;
    if (node < N) {
        int lo = row_off[node] - base;
        int hi = row_off[node + 1] - base;
        for (int i = lo + 1; i < hi; ++i) {
            int key = sE[i];
            int j = i - 1;
            while (j >= lo && sE[j] > key) { sE[j + 1] = sE[j]; --j; }
            sE[j + 1] = key;
        }
    }
    __syncthreads();
    for (int i = t; i < cnt; i += 512) csr_src[base + i] = sE[i];
}

// ---- MFMA GEMM (layer 1 only) ---------------------------------------------
template <int K, bool BF16IN>
__global__ __launch_bounds__(256) void k_gemm_mfma(const void* __restrict__ xin,
                                                   const float* __restrict__ W,
                                                   const float* __restrict__ dinv,
                                                   unsigned short* __restrict__ out,
                                                   int N) {
    constexpr int KS = K + 8;
    __shared__ short sX[64 * KS];
    __shared__ short sW[64 * KS];
    const int tid = threadIdx.x;
    const int wv = tid >> 6, lane = tid & 63;
    const int q = lane >> 4, m = lane & 15;
    const int nb = blockIdx.x * 64;

    for (int i = tid; i < K * 64; i += 256) {
        int k = i >> 6, c = i & 63;
        sW[c * KS + k] = (short)f2bf(W[i]);
    }
    if (BF16IN) {
        const unsigned short* xb = (const unsigned short*)xin;
        for (int i = tid; i < 64 * (K / 8); i += 256) {
            int r = i / (K / 8), c8 = (i % (K / 8)) * 8;
            int node = nb + r;
            uint4 v = make_uint4(0u, 0u, 0u, 0u);
            if (node < N) v = *(const uint4*)(xb + (size_t)node * K + c8);
            *(uint4*)(&sX[r * KS + c8]) = v;
        }
    } else {
        const float* xf = (const float*)xin;
        for (int i = tid; i < 64 * (K / 8); i += 256) {
            int r = i / (K / 8), c8 = (i % (K / 8)) * 8;
            int node = nb + r;
            uint4 v = make_uint4(0u, 0u, 0u, 0u);
            if (node < N) {
                float4 lo = *(const float4*)(xf + (size_t)node * K + c8);
                float4 hi = *(const float4*)(xf + (size_t)node * K + c8 + 4);
                v.x = packbf(lo.x, lo.y);
                v.y = packbf(lo.z, lo.w);
                v.z = packbf(hi.x, hi.y);
                v.w = packbf(hi.z, hi.w);
            }
            *(uint4*)(&sX[r * KS + c8]) = v;
        }
    }
    __syncthreads();

    f32x4 acc[4] = {};
    const short* aRow = &sX[(wv * 16 + m) * KS + q * 8];
#pragma unroll
    for (int k0 = 0; k0 < K; k0 += 32) {
        bf16x8 a = *(const bf16x8*)(aRow + k0);
#pragma unroll
        for (int ft = 0; ft < 4; ++ft) {
            bf16x8 b = *(const bf16x8*)(&sW[(ft * 16 + m) * KS + k0 + q * 8]);
            acc[ft] = __builtin_amdgcn_mfma_f32_16x16x32_bf16(a, b, acc[ft], 0, 0, 0);
        }
    }
#pragma unroll
    for (int r = 0; r < 4; ++r) {
        int node = nb + wv * 16 + q * 4 + r;
        if (node < N) {
            float di = dinv[node];
#pragma unroll
            for (int ft = 0; ft < 4; ++ft)
                out[(size_t)node * 64 + ft * 16 + m] = f2bf(acc[ft][r] * di);
        }
    }
}

// ---- fused layer-1 agg + gemm2 (R14 structure) ----------------------------
// Phase A (gather): 8 nodes/wave, slot s=lane>>3 owns node, octet o=lane&7
// owns feats [8o,8o+8); 4-way prefetched gather chains; self = virtual edge.
// Phase B (gemm2): wave writes its 8 h1 rows (bf16) into a private LDS
// A-tile (rows 8-15 zero), 8 mfma_16x16x32_bf16 vs LDS W2^T, dinv -> xl2.
__global__ __launch_bounds__(256) void k_agg_g2(const unsigned short* __restrict__ xl,
                                                const int* __restrict__ row_off,
                                                const int* __restrict__ csr_src,
                                                const float* __restrict__ dinv,
                                                const float* __restrict__ bias,
                                                const float* __restrict__ W2,
                                                unsigned short* __restrict__ out, int N) {
    constexpr int KS = 72;               // 64 + 8 pad (bf16 elems)
    __shared__ short sH[4 * 16 * KS];    // per-wave 16x64 A-tiles (9KB)
    __shared__ short sW2[64 * KS];       // W2^T bf16 (9KB)
    const int tid = threadIdx.x;
    const int wv = tid >> 6, lane = tid & 63;
    const int s = lane >> 3, o = lane & 7;
    const int q = lane >> 4, m = lane & 15;

    // stage W2 transposed bf16: sW2[n*KS+k] = bf16(W2[k*64+n])
    for (int i = tid; i < 64 * 64; i += 256) {
        int k = i >> 6, n = i & 63;
        sW2[n * KS + k] = (short)f2bf(W2[i]);
    }
    // zero this wave's A-tile rows 8-15 (never written by gather phase)
    short* myH = &sH[wv * 16 * KS];
    for (int i = lane; i < 8 * KS / 4; i += 64)
        ((unsigned long long*)(myH + 8 * KS))[i] = 0ull;
    __syncthreads();                     // sW2 visible to all waves

    const int base8 = (blockIdx.x * 4 + wv) * 8;
    int node = base8 + s;
    const bool active = node < N;
    node = min(node, N - 1);
    const int beg = row_off[node];
    const int deg = row_off[node + 1] - beg;
    const int cnt = active ? deg + 1 : 0;
    int mx = cnt;
    mx = max(mx, __shfl_xor(mx, 8, 64));
    mx = max(mx, __shfl_xor(mx, 16, 64));
    mx = max(mx, __shfl_xor(mx, 32, 64));
    const char* xlb = (const char*)xl;
    const unsigned loff = (unsigned)(o << 4);
    f32x2 acc0[4] = {}, acc1[4] = {};
    int idx[4];
#pragma unroll
    for (int j = 0; j < 4; ++j) idx[j] = (j < deg) ? csr_src[beg + j] : node;
    for (int it = 0; it < mx; it += 4) {
        int c[4];
        bool v[4];
#pragma unroll
        for (int j = 0; j < 4; ++j) {
            c[j] = idx[j];
            v[j] = (it + j) < cnt;
            idx[j] = (it + 4 + j < deg) ? csr_src[beg + it + 4 + j] : node;
        }
        uint4 g0 = *(const uint4*)(xlb + (((unsigned)c[0] << 7) | loff));
        uint4 g1 = *(const uint4*)(xlb + (((unsigned)c[1] << 7) | loff));
        uint4 g2 = *(const uint4*)(xlb + (((unsigned)c[2] << 7) | loff));
        uint4 g3 = *(const uint4*)(xlb + (((unsigned)c[3] << 7) | loff));
        if (!v[0]) g0 = make_uint4(0u, 0u, 0u, 0u);
        if (!v[1]) g1 = make_uint4(0u, 0u, 0u, 0u);
        if (!v[2]) g2 = make_uint4(0u, 0u, 0u, 0u);
        if (!v[3]) g3 = make_uint4(0u, 0u, 0u, 0u);
        upadd2(g0, acc0);
        upadd2(g1, acc1);
        upadd2(g2, acc0);
        upadd2(g3, acc1);
    }
#pragma unroll
    for (int j = 0; j < 4; ++j) acc0[j] += acc1[j];
    // h1 row -> LDS A-tile (bf16), row = slot s
    {
        float di = dinv[node];
        float4 blo = *(const float4*)(bias + o * 8);
        float4 bhi = *(const float4*)(bias + o * 8 + 4);
        uint4 h;
        h.x = packbf(fmaxf(acc0[0].x * di + blo.x, 0.f), fmaxf(acc0[0].y * di + blo.y, 0.f));
        h.y = packbf(fmaxf(acc0[1].x * di + blo.z, 0.f), fmaxf(acc0[1].y * di + blo.w, 0.f));
        h.z = packbf(fmaxf(acc0[2].x * di + bhi.x, 0.f), fmaxf(acc0[2].y * di + bhi.y, 0.f));
        h.w = packbf(fmaxf(acc0[3].x * di + bhi.z, 0.f), fmaxf(acc0[3].y * di + bhi.w, 0.f));
        *(uint4*)(myH + s * KS + o * 8) = h;     // same-wave LDS, no barrier
    }
    // gemm2: 8 MFMA (4 feat-tiles x K=64)
    f32x4 accm[4] = {};
#pragma unroll
    for (int k0 = 0; k0 < 64; k0 += 32) {
        bf16x8 a = *(const bf16x8*)(myH + m * KS + q * 8 + k0);
#pragma unroll
        for (int ft = 0; ft < 4; ++ft) {
            bf16x8 b = *(const bf16x8*)(&sW2[(ft * 16 + m) * KS + k0 + q * 8]);
            accm[ft] = __builtin_amdgcn_mfma_f32_16x16x32_bf16(a, b, accm[ft], 0, 0, 0);
        }
    }
    if (q < 2) {                          // valid rows 0..7
#pragma unroll
        for (int r = 0; r < 4; ++r) {
            int node2 = base8 + q * 4 + r;
            if (node2 < N) {
                float di2 = dinv[node2];
#pragma unroll
                for (int ft = 0; ft < 4; ++ft)
                    out[(size_t)node2 * 64 + ft * 16 + m] = f2bf(accm[ft][r] * di2);
            }
        }
    }
}

// Layer-2 agg + final FC + sigmoid (4-way chains; octet fold shfl 1/2/4).
__global__ __launch_bounds__(256) void k_agg_fc(const unsigned short* __restrict__ xl,
                                                const int* __restrict__ row_off,
                                                const int* __restrict__ csr_src,
                                                const float* __restrict__ dinv,
                                                const float* __restrict__ bias,
                                                const float* __restrict__ Wfc,
                                                const float* __restrict__ bfc,
                                                float* __restrict__ out, int N) {
    const int wave = threadIdx.x >> 6, lane = threadIdx.x & 63;
    const int s = lane >> 3, o = lane & 7;
    int node = (blockIdx.x * 4 + wave) * 8 + s;
    const bool active = node < N;
    node = min(node, N - 1);
    const int beg = row_off[node];
    const int deg = row_off[node + 1] - beg;
    const int cnt = active ? deg + 1 : 0;
    int mx = cnt;
    mx = max(mx, __shfl_xor(mx, 8, 64));
    mx = max(mx, __shfl_xor(mx, 16, 64));
    mx = max(mx, __shfl_xor(mx, 32, 64));
    const char* xlb = (const char*)xl;
    const unsigned loff = (unsigned)(o << 4);
    f32x2 acc0[4] = {}, acc1[4] = {};
    int idx[4];
#pragma unroll
    for (int j = 0; j < 4; ++j) idx[j] = (j < deg) ? csr_src[beg + j] : node;
    for (int it = 0; it < mx; it += 4) {
        int c[4];
        bool v[4];
#pragma unroll
        for (int j = 0; j < 4; ++j) {
            c[j] = idx[j];
            v[j] = (it + j) < cnt;
            idx[j] = (it + 4 + j < deg) ? csr_src[beg + it + 4 + j] : node;
        }
        uint4 g0 = *(const uint4*)(xlb + (((unsigned)c[0] << 7) | loff));
        uint4 g1 = *(const uint4*)(xlb + (((unsigned)c[1] << 7) | loff));
        uint4 g2 = *(const uint4*)(xlb + (((unsigned)c[2] << 7) | loff));
        uint4 g3 = *(const uint4*)(xlb + (((unsigned)c[3] << 7) | loff));
        if (!v[0]) g0 = make_uint4(0u, 0u, 0u, 0u);
        if (!v[1]) g1 = make_uint4(0u, 0u, 0u, 0u);
        if (!v[2]) g2 = make_uint4(0u, 0u, 0u, 0u);
        if (!v[3]) g3 = make_uint4(0u, 0u, 0u, 0u);
        upadd2(g0, acc0);
        upadd2(g1, acc1);
        upadd2(g2, acc0);
        upadd2(g3, acc1);
    }
#pragma unroll
    for (int j = 0; j < 4; ++j) acc0[j] += acc1[j];
    const float di = dinv[node];
    float4 blo = *(const float4*)(bias + o * 8);
    float4 bhi = *(const float4*)(bias + o * 8 + 4);
    float4 wlo = *(const float4*)(Wfc + o * 8);
    float4 whi = *(const float4*)(Wfc + o * 8 + 4);
    float v = 0.f;
    v += fmaxf(acc0[0].x * di + blo.x, 0.f) * wlo.x;
    v += fmaxf(acc0[0].y * di + blo.y, 0.f) * wlo.y;
    v += fmaxf(acc0[1].x * di + blo.z, 0.f) * wlo.z;
    v += fmaxf(acc0[1].y * di + blo.w, 0.f) * wlo.w;
    v += fmaxf(acc0[2].x * di + bhi.x, 0.f) * whi.x;
    v += fmaxf(acc0[2].y * di + bhi.y, 0.f) * whi.y;
    v += fmaxf(acc0[3].x * di + bhi.z, 0.f) * whi.z;
    v += fmaxf(acc0[3].y * di + bhi.w, 0.f) * whi.w;
    v += __shfl_xor(v, 1, 64);
    v += __shfl_xor(v, 2, 64);
    v += __shfl_xor(v, 4, 64);
    if (active && o == 0) out[node] = 1.f / (1.f + expf(-(v + bfc[0])));
}

extern "C" void kernel_launch(void* const* d_in, const int* in_sizes, int n_in,
                              void* d_out, int out_size, void* d_ws, size_t ws_size,
                              hipStream_t stream) {
    const float* x   = (const float*)d_in[0];
    const int*   ei  = (const int*)d_in[1];   // [2, E]: row then col
    const float* W1  = (const float*)d_in[2];
    const float* b1  = (const float*)d_in[3];
    const float* W2  = (const float*)d_in[4];
    const float* b2  = (const float*)d_in[5];
    const float* Wfc = (const float*)d_in[6];
    const float* bfc = (const float*)d_in[7];
    float* out = (float*)d_out;

    const int H = in_sizes[3];          // 64
    const int D = in_sizes[2] / H;      // 128
    const int N = in_sizes[0] / D;      // 100000
    const int E = in_sizes[1] / 2;      // 1600000
    const int* row = ei;
    const int* col = ei + E;
    const int NBUK = (N + 511) >> 9;    // 196 buckets of 512 nodes
    const int CH   = (E + CHUNKS - 1) / CHUNKS;

    // Workspace carve-up (256B aligned slices)
    char* p = (char*)d_ws;
    auto carve = [&](size_t bytes) {
        char* r = p;
        p += (bytes + 255) & ~(size_t)255;
        return (void*)r;
    };
    int*            hist_g      = (int*)carve((size_t)CHUNKS * 256 * 4);
    int*            histOff     = (int*)carve((size_t)256 * CHUNKS * 4);
    int*            bucketTotal = (int*)carve((size_t)256 * 4);
    int*            bucketBase  = (int*)carve((size_t)256 * 4);
    unsigned*       ebuf        = (unsigned*)carve((size_t)E * 4);
    int*            csr_src     = (int*)carve((size_t)E * 4);
    int*            row_off     = (int*)carve((size_t)(N + 1) * 4);
    float*          dinv        = (float*)carve((size_t)N * 4);
    unsigned short* bufXL       = (unsigned short*)carve((size_t)N * 64 * 2);
    unsigned short* bufXL2      = (unsigned short*)carve((size_t)N * 64 * 2);
    (void)ws_size;

    const int TB = 256;
    // 1. CSR build (bucketed counting sort; no global atomics)
    k_hist<<<CHUNKS, TB, 0, stream>>>(col, E, NBUK, CH, hist_g);
    k_colscan<<<NBUK, TB, 0, stream>>>(hist_g, NBUK, histOff, bucketTotal);
    k_scan_tot<<<1, TB, 0, stream>>>(bucketTotal, NBUK, E, N, bucketBase, row_off);
    k_scatter<<<CHUNKS, TB, 0, stream>>>(row, col, E, NBUK, CH, bucketBase, histOff, ebuf);
    k_bucket<<<NBUK, 512, 0, stream>>>(ebuf, bucketBase, bucketTotal, N,
                                       row_off, dinv, csr_src);
    // 1b. R18: sort each adjacency list ascending by src (L2-window locality)
    k_sortadj<<<NBUK, 512, 0, stream>>>(row_off, bucketBase, bucketTotal, N, csr_src);

    int gemmGrid = (N + 63) / 64;       // 1563
    int aggGrid  = (N + 31) / 32;       // 3125 (8 nodes/wave x 4 waves)
    // 2. layer 1 GEMM: xl = bf16((x@W1)*dinv)
    k_gemm_mfma<128, false><<<gemmGrid, TB, 0, stream>>>(x, W1, dinv, bufXL, N);
    // 3. fused layer-1 agg + gemm2: xl2 = bf16(dinv*(relu(dinv*Agg(xl)+b1)@W2))
    k_agg_g2<<<aggGrid, TB, 0, stream>>>(bufXL, row_off, csr_src, dinv, b1, W2, bufXL2, N);
    // 4. layer-2 agg + FC + sigmoid
    k_agg_fc<<<aggGrid, TB, 0, stream>>>(bufXL2, row_off, csr_src, dinv, b2, Wfc, bfc, out, N);
}

// Round 6
// 243.770 us; speedup vs baseline: 1.1785x; 1.0813x over previous
//
#include <hip/hip_runtime.h>
#include <math.h>

// ---------------------------------------------------------------------------
// GCN: h1 = relu(Agg(x@W1)+b1); h2 = relu(Agg(h1@W2)+b2); out = sigmoid(h2@Wfc+bfc)
// Agg(xl)[dst] = dinv[dst] * ( sum_{src->dst} xl_s[src] + xl_s[dst] )
//   where xl_s[n] = (x@W)[n] * dinv[n]   (source-side norm folded into GEMM)
// R2-R9: scan / dinv-fold / counting-sort CSR (no global atomics).
// R10: MFMA GEMMs. R11-R14: node-per-slot gather aggs + fused gemm2 (41.5us).
// R15: 8-way chains -> NULL => not per-wave chain-depth-bound.
// R16: edge-parallel 2-deep -> 76us REGRESSION => concurrency saturates.
// R17: degree-balanced perm -> NULL (+49us helper). R18: src-sorted lists ->
//      ~NULL on aggs (+51us sort).  Evidence stack: gather service pinned at
//      ~5.2TB/s (1 line/13cy/CU) regardless of offered concurrency, balance,
//      or temporal locality => fixed per-CU in-flight miss cap (L1 MSHR-ish).
// R19: bypass L1 on the gather loads (__builtin_nontemporal_load): table
//      never hits 32KB L1 anyway; NT policy skips L1 allocation so misses
//      ride the vmcnt path (63/wave) instead of the L1 miss-tracking pool.
//      csr index loads stay cached (sequential, L1-friendly).
//      (fix: NT builtin needs ext_vector_type, not HIP uint4 struct)
// ---------------------------------------------------------------------------

typedef __attribute__((ext_vector_type(8))) short bf16x8;
typedef __attribute__((ext_vector_type(4))) float f32x4;
typedef __attribute__((ext_vector_type(2))) float f32x2;
typedef __attribute__((ext_vector_type(4))) unsigned u32x4;

#define CHUNKS 1024

__device__ __forceinline__ unsigned short f2bf(float f) {
    unsigned u = __float_as_uint(f);
    u += 0x7FFFu + ((u >> 16) & 1u);   // round-to-nearest-even
    return (unsigned short)(u >> 16);
}
__device__ __forceinline__ unsigned packbf(float a, float b) {
    return (unsigned)f2bf(a) | ((unsigned)f2bf(b) << 16);
}
// accumulate 8 bf16 (one uint4) into 4 packed f32x2 accumulators
__device__ __forceinline__ void upadd2(uint4 g, f32x2* a) {
    a[0] += (f32x2){__uint_as_float(g.x << 16), __uint_as_float(g.x & 0xFFFF0000u)};
    a[1] += (f32x2){__uint_as_float(g.y << 16), __uint_as_float(g.y & 0xFFFF0000u)};
    a[2] += (f32x2){__uint_as_float(g.z << 16), __uint_as_float(g.z & 0xFFFF0000u)};
    a[3] += (f32x2){__uint_as_float(g.w << 16), __uint_as_float(g.w & 0xFFFF0000u)};
}
// NT gather: bypass L1 allocation (gather table never L1-hits anyway)
__device__ __forceinline__ uint4 ldnt(const void* p) {
    u32x4 v = __builtin_nontemporal_load((const u32x4*)p);
    return make_uint4(v.x, v.y, v.z, v.w);
}

// ---- CSR build: bucketed counting sort (no global atomics) ----------------
__global__ __launch_bounds__(256) void k_hist(const int* __restrict__ col, int E,
                                              int NBUK, int CH,
                                              int* __restrict__ hist_g) {
    __shared__ int h[256];
    for (int i = threadIdx.x; i < NBUK; i += 256) h[i] = 0;
    __syncthreads();
    int base = blockIdx.x * CH, hi = min(base + CH, E);
    for (int e = base + (int)threadIdx.x; e < hi; e += 256)
        atomicAdd(&h[col[e] >> 9], 1);
    __syncthreads();
    for (int i = threadIdx.x; i < NBUK; i += 256)
        hist_g[blockIdx.x * NBUK + i] = h[i];
}

__global__ __launch_bounds__(256) void k_colscan(const int* __restrict__ hist_g, int NBUK,
                                                 int* __restrict__ histOff,
                                                 int* __restrict__ bucketTotal) {
    __shared__ int s[256];
    const int b = blockIdx.x, t = threadIdx.x;
    int v[4], sum = 0;
#pragma unroll
    for (int j = 0; j < 4; ++j) {
        v[j] = hist_g[(t * 4 + j) * NBUK + b];
        sum += v[j];
    }
    s[t] = sum;
    __syncthreads();
    for (int off = 1; off < 256; off <<= 1) {
        int u = (t >= off) ? s[t - off] : 0;
        __syncthreads();
        s[t] += u;
        __syncthreads();
    }
    int run = s[t] - sum;
#pragma unroll
    for (int j = 0; j < 4; ++j) {
        histOff[b * CHUNKS + t * 4 + j] = run;
        run += v[j];
    }
    if (t == 255) bucketTotal[b] = run;
}

__global__ __launch_bounds__(256) void k_scan_tot(const int* __restrict__ bucketTotal,
                                                  int NBUK, int E, int N,
                                                  int* __restrict__ bucketBase,
                                                  int* __restrict__ row_off) {
    __shared__ int s[256];
    int t = threadIdx.x;
    int v = (t < NBUK) ? bucketTotal[t] : 0;
    s[t] = v;
    __syncthreads();
    for (int off = 1; off < 256; off <<= 1) {
        int u = (t >= off) ? s[t - off] : 0;
        __syncthreads();
        s[t] += u;
        __syncthreads();
    }
    if (t < NBUK) bucketBase[t] = s[t] - v;
    if (t == 0) row_off[N] = E;
}

__global__ __launch_bounds__(256) void k_scatter(const int* __restrict__ row,
                                                 const int* __restrict__ col, int E,
                                                 int NBUK, int CH,
                                                 const int* __restrict__ bucketBase,
                                                 const int* __restrict__ histOff,
                                                 unsigned* __restrict__ ebuf) {
    __shared__ int cur[256];
    for (int i = threadIdx.x; i < NBUK; i += 256)
        cur[i] = bucketBase[i] + histOff[i * CHUNKS + blockIdx.x];
    __syncthreads();
    int base = blockIdx.x * CH, hi = min(base + CH, E);
    for (int e = base + (int)threadIdx.x; e < hi; e += 256) {
        int d = col[e], src = row[e];
        int b = d >> 9;
        int pos = atomicAdd(&cur[b], 1);             // LDS atomic
        ebuf[pos] = ((unsigned)(d & 511) << 17) | (unsigned)src;
    }
}

__global__ __launch_bounds__(512) void k_bucket(const unsigned* __restrict__ ebuf,
                                                const int* __restrict__ bucketBase,
                                                const int* __restrict__ bucketTotal,
                                                int N,
                                                int* __restrict__ row_off,
                                                float* __restrict__ dinv,
                                                int* __restrict__ csr_src) {
    __shared__ int hc[512], of[512];
    const int bid = blockIdx.x, t = threadIdx.x;
    const int base = bucketBase[bid];
    const int cnt  = bucketTotal[bid];
    hc[t] = 0;
    __syncthreads();
    for (int i = t; i < cnt; i += 512)
        atomicAdd(&hc[ebuf[base + i] >> 17], 1);
    __syncthreads();
    int v = hc[t];
    of[t] = v;
    __syncthreads();
    for (int off = 1; off < 512; off <<= 1) {
        int u = (t >= off) ? of[t - off] : 0;
        __syncthreads();
        of[t] += u;
        __syncthreads();
    }
    int excl = of[t] - v;
    int node = bid * 512 + t;
    if (node < N) {
        row_off[node] = base + excl;
        dinv[node] = rsqrtf((float)(v + 1));   // +1 self loop
    }
    of[t] = excl;
    __syncthreads();
    for (int i = t; i < cnt; i += 512) {
        unsigned e = ebuf[base + i];
        int dl = (int)(e >> 17), src = (int)(e & 0x1FFFFu);
        int pos = atomicAdd(&of[dl], 1);       // LDS atomic
        csr_src[base + pos] = src;
    }
}

// ---- MFMA GEMM (layer 1 only) ---------------------------------------------
template <int K, bool BF16IN>
__global__ __launch_bounds__(256) void k_gemm_mfma(const void* __restrict__ xin,
                                                   const float* __restrict__ W,
                                                   const float* __restrict__ dinv,
                                                   unsigned short* __restrict__ out,
                                                   int N) {
    constexpr int KS = K + 8;
    __shared__ short sX[64 * KS];
    __shared__ short sW[64 * KS];
    const int tid = threadIdx.x;
    const int wv = tid >> 6, lane = tid & 63;
    const int q = lane >> 4, m = lane & 15;
    const int nb = blockIdx.x * 64;

    for (int i = tid; i < K * 64; i += 256) {
        int k = i >> 6, c = i & 63;
        sW[c * KS + k] = (short)f2bf(W[i]);
    }
    if (BF16IN) {
        const unsigned short* xb = (const unsigned short*)xin;
        for (int i = tid; i < 64 * (K / 8); i += 256) {
            int r = i / (K / 8), c8 = (i % (K / 8)) * 8;
            int node = nb + r;
            uint4 v = make_uint4(0u, 0u, 0u, 0u);
            if (node < N) v = *(const uint4*)(xb + (size_t)node * K + c8);
            *(uint4*)(&sX[r * KS + c8]) = v;
        }
    } else {
        const float* xf = (const float*)xin;
        for (int i = tid; i < 64 * (K / 8); i += 256) {
            int r = i / (K / 8), c8 = (i % (K / 8)) * 8;
            int node = nb + r;
            uint4 v = make_uint4(0u, 0u, 0u, 0u);
            if (node < N) {
                float4 lo = *(const float4*)(xf + (size_t)node * K + c8);
                float4 hi = *(const float4*)(xf + (size_t)node * K + c8 + 4);
                v.x = packbf(lo.x, lo.y);
                v.y = packbf(lo.z, lo.w);
                v.z = packbf(hi.x, hi.y);
                v.w = packbf(hi.z, hi.w);
            }
            *(uint4*)(&sX[r * KS + c8]) = v;
        }
    }
    __syncthreads();

    f32x4 acc[4] = {};
    const short* aRow = &sX[(wv * 16 + m) * KS + q * 8];
#pragma unroll
    for (int k0 = 0; k0 < K; k0 += 32) {
        bf16x8 a = *(const bf16x8*)(aRow + k0);
#pragma unroll
        for (int ft = 0; ft < 4; ++ft) {
            bf16x8 b = *(const bf16x8*)(&sW[(ft * 16 + m) * KS + k0 + q * 8]);
            acc[ft] = __builtin_amdgcn_mfma_f32_16x16x32_bf16(a, b, acc[ft], 0, 0, 0);
        }
    }
#pragma unroll
    for (int r = 0; r < 4; ++r) {
        int node = nb + wv * 16 + q * 4 + r;
        if (node < N) {
            float di = dinv[node];
#pragma unroll
            for (int ft = 0; ft < 4; ++ft)
                out[(size_t)node * 64 + ft * 16 + m] = f2bf(acc[ft][r] * di);
        }
    }
}

// ---- fused layer-1 agg + gemm2 --------------------------------------------
// Phase A (gather): 8 nodes/wave, slot s=lane>>3 owns node, octet o=lane&7
// owns feats [8o,8o+8); 4-way prefetched gather chains (NT loads, no L1
// alloc); self = virtual edge.
// Phase B (gemm2): wave writes its 8 h1 rows (bf16) into a private LDS
// A-tile (rows 8-15 zero), 8 mfma_16x16x32_bf16 vs LDS W2^T, dinv -> xl2.
__global__ __launch_bounds__(256) void k_agg_g2(const unsigned short* __restrict__ xl,
                                                const int* __restrict__ row_off,
                                                const int* __restrict__ csr_src,
                                                const float* __restrict__ dinv,
                                                const float* __restrict__ bias,
                                                const float* __restrict__ W2,
                                                unsigned short* __restrict__ out, int N) {
    constexpr int KS = 72;               // 64 + 8 pad (bf16 elems)
    __shared__ short sH[4 * 16 * KS];    // per-wave 16x64 A-tiles (9KB)
    __shared__ short sW2[64 * KS];       // W2^T bf16 (9KB)
    const int tid = threadIdx.x;
    const int wv = tid >> 6, lane = tid & 63;
    const int s = lane >> 3, o = lane & 7;
    const int q = lane >> 4, m = lane & 15;

    // stage W2 transposed bf16: sW2[n*KS+k] = bf16(W2[k*64+n])
    for (int i = tid; i < 64 * 64; i += 256) {
        int k = i >> 6, n = i & 63;
        sW2[n * KS + k] = (short)f2bf(W2[i]);
    }
    // zero this wave's A-tile rows 8-15 (never written by gather phase)
    short* myH = &sH[wv * 16 * KS];
    for (int i = lane; i < 8 * KS / 4; i += 64)
        ((unsigned long long*)(myH + 8 * KS))[i] = 0ull;
    __syncthreads();                     // sW2 visible to all waves

    const int base8 = (blockIdx.x * 4 + wv) * 8;
    int node = base8 + s;
    const bool active = node < N;
    node = min(node, N - 1);
    const int beg = row_off[node];
    const int deg = row_off[node + 1] - beg;
    const int cnt = active ? deg + 1 : 0;
    int mx = cnt;
    mx = max(mx, __shfl_xor(mx, 8, 64));
    mx = max(mx, __shfl_xor(mx, 16, 64));
    mx = max(mx, __shfl_xor(mx, 32, 64));
    const char* xlb = (const char*)xl;
    const unsigned loff = (unsigned)(o << 4);
    f32x2 acc0[4] = {}, acc1[4] = {};
    int idx[4];
#pragma unroll
    for (int j = 0; j < 4; ++j) idx[j] = (j < deg) ? csr_src[beg + j] : node;
    for (int it = 0; it < mx; it += 4) {
        int c[4];
        bool v[4];
#pragma unroll
        for (int j = 0; j < 4; ++j) {
            c[j] = idx[j];
            v[j] = (it + j) < cnt;
            idx[j] = (it + 4 + j < deg) ? csr_src[beg + it + 4 + j] : node;
        }
        uint4 g0 = ldnt(xlb + (((unsigned)c[0] << 7) | loff));
        uint4 g1 = ldnt(xlb + (((unsigned)c[1] << 7) | loff));
        uint4 g2 = ldnt(xlb + (((unsigned)c[2] << 7) | loff));
        uint4 g3 = ldnt(xlb + (((unsigned)c[3] << 7) | loff));
        if (!v[0]) g0 = make_uint4(0u, 0u, 0u, 0u);
        if (!v[1]) g1 = make_uint4(0u, 0u, 0u, 0u);
        if (!v[2]) g2 = make_uint4(0u, 0u, 0u, 0u);
        if (!v[3]) g3 = make_uint4(0u, 0u, 0u, 0u);
        upadd2(g0, acc0);
        upadd2(g1, acc1);
        upadd2(g2, acc0);
        upadd2(g3, acc1);
    }
#pragma unroll
    for (int j = 0; j < 4; ++j) acc0[j] += acc1[j];
    // h1 row -> LDS A-tile (bf16), row = slot s
    {
        float di = dinv[node];
        float4 blo = *(const float4*)(bias + o * 8);
        float4 bhi = *(const float4*)(bias + o * 8 + 4);
        uint4 h;
        h.x = packbf(fmaxf(acc0[0].x * di + blo.x, 0.f), fmaxf(acc0[0].y * di + blo.y, 0.f));
        h.y = packbf(fmaxf(acc0[1].x * di + blo.z, 0.f), fmaxf(acc0[1].y * di + blo.w, 0.f));
        h.z = packbf(fmaxf(acc0[2].x * di + bhi.x, 0.f), fmaxf(acc0[2].y * di + bhi.y, 0.f));
        h.w = packbf(fmaxf(acc0[3].x * di + bhi.z, 0.f), fmaxf(acc0[3].y * di + bhi.w, 0.f));
        *(uint4*)(myH + s * KS + o * 8) = h;     // same-wave LDS, no barrier
    }
    // gemm2: 8 MFMA (4 feat-tiles x K=64)
    f32x4 accm[4] = {};
#pragma unroll
    for (int k0 = 0; k0 < 64; k0 += 32) {
        bf16x8 a = *(const bf16x8*)(myH + m * KS + q * 8 + k0);
#pragma unroll
        for (int ft = 0; ft < 4; ++ft) {
            bf16x8 b = *(const bf16x8*)(&sW2[(ft * 16 + m) * KS + k0 + q * 8]);
            accm[ft] = __builtin_amdgcn_mfma_f32_16x16x32_bf16(a, b, accm[ft], 0, 0, 0);
        }
    }
    if (q < 2) {                          // valid rows 0..7
#pragma unroll
        for (int r = 0; r < 4; ++r) {
            int node2 = base8 + q * 4 + r;
            if (node2 < N) {
                float di2 = dinv[node2];
#pragma unroll
                for (int ft = 0; ft < 4; ++ft)
                    out[(size_t)node2 * 64 + ft * 16 + m] = f2bf(accm[ft][r] * di2);
            }
        }
    }
}

// Layer-2 agg + final FC + sigmoid (4-way NT chains; octet fold shfl 1/2/4).
__global__ __launch_bounds__(256) void k_agg_fc(const unsigned short* __restrict__ xl,
                                                const int* __restrict__ row_off,
                                                const int* __restrict__ csr_src,
                                                const float* __restrict__ dinv,
                                                const float* __restrict__ bias,
                                                const float* __restrict__ Wfc,
                                                const float* __restrict__ bfc,
                                                float* __restrict__ out, int N) {
    const int wave = threadIdx.x >> 6, lane = threadIdx.x & 63;
    const int s = lane >> 3, o = lane & 7;
    int node = (blockIdx.x * 4 + wave) * 8 + s;
    const bool active = node < N;
    node = min(node, N - 1);
    const int beg = row_off[node];
    const int deg = row_off[node + 1] - beg;
    const int cnt = active ? deg + 1 : 0;
    int mx = cnt;
    mx = max(mx, __shfl_xor(mx, 8, 64));
    mx = max(mx, __shfl_xor(mx, 16, 64));
    mx = max(mx, __shfl_xor(mx, 32, 64));
    const char* xlb = (const char*)xl;
    const unsigned loff = (unsigned)(o << 4);
    f32x2 acc0[4] = {}, acc1[4] = {};
    int idx[4];
#pragma unroll
    for (int j = 0; j < 4; ++j) idx[j] = (j < deg) ? csr_src[beg + j] : node;
    for (int it = 0; it < mx; it += 4) {
        int c[4];
        bool v[4];
#pragma unroll
        for (int j = 0; j < 4; ++j) {
            c[j] = idx[j];
            v[j] = (it + j) < cnt;
            idx[j] = (it + 4 + j < deg) ? csr_src[beg + it + 4 + j] : node;
        }
        uint4 g0 = ldnt(xlb + (((unsigned)c[0] << 7) | loff));
        uint4 g1 = ldnt(xlb + (((unsigned)c[1] << 7) | loff));
        uint4 g2 = ldnt(xlb + (((unsigned)c[2] << 7) | loff));
        uint4 g3 = ldnt(xlb + (((unsigned)c[3] << 7) | loff));
        if (!v[0]) g0 = make_uint4(0u, 0u, 0u, 0u);
        if (!v[1]) g1 = make_uint4(0u, 0u, 0u, 0u);
        if (!v[2]) g2 = make_uint4(0u, 0u, 0u, 0u);
        if (!v[3]) g3 = make_uint4(0u, 0u, 0u, 0u);
        upadd2(g0, acc0);
        upadd2(g1, acc1);
        upadd2(g2, acc0);
        upadd2(g3, acc1);
    }
#pragma unroll
    for (int j = 0; j < 4; ++j) acc0[j] += acc1[j];
    const float di = dinv[node];
    float4 blo = *(const float4*)(bias + o * 8);
    float4 bhi = *(const float4*)(bias + o * 8 + 4);
    float4 wlo = *(const float4*)(Wfc + o * 8);
    float4 whi = *(const float4*)(Wfc + o * 8 + 4);
    float v = 0.f;
    v += fmaxf(acc0[0].x * di + blo.x, 0.f) * wlo.x;
    v += fmaxf(acc0[0].y * di + blo.y, 0.f) * wlo.y;
    v += fmaxf(acc0[1].x * di + blo.z, 0.f) * wlo.z;
    v += fmaxf(acc0[1].y * di + blo.w, 0.f) * wlo.w;
    v += fmaxf(acc0[2].x * di + bhi.x, 0.f) * whi.x;
    v += fmaxf(acc0[2].y * di + bhi.y, 0.f) * whi.y;
    v += fmaxf(acc0[3].x * di + bhi.z, 0.f) * whi.z;
    v += fmaxf(acc0[3].y * di + bhi.w, 0.f) * whi.w;
    v += __shfl_xor(v, 1, 64);
    v += __shfl_xor(v, 2, 64);
    v += __shfl_xor(v, 4, 64);
    if (active && o == 0) out[node] = 1.f / (1.f + expf(-(v + bfc[0])));
}

extern "C" void kernel_launch(void* const* d_in, const int* in_sizes, int n_in,
                              void* d_out, int out_size, void* d_ws, size_t ws_size,
                              hipStream_t stream) {
    const float* x   = (const float*)d_in[0];
    const int*   ei  = (const int*)d_in[1];   // [2, E]: row then col
    const float* W1  = (const float*)d_in[2];
    const float* b1  = (const float*)d_in[3];
    const float* W2  = (const float*)d_in[4];
    const float* b2  = (const float*)d_in[5];
    const float* Wfc = (const float*)d_in[6];
    const float* bfc = (const float*)d_in[7];
    float* out = (float*)d_out;

    const int H = in_sizes[3];          // 64
    const int D = in_sizes[2] / H;      // 128
    const int N = in_sizes[0] / D;      // 100000
    const int E = in_sizes[1] / 2;      // 1600000
    const int* row = ei;
    const int* col = ei + E;
    const int NBUK = (N + 511) >> 9;    // 196 buckets of 512 nodes
    const int CH   = (E + CHUNKS - 1) / CHUNKS;

    // Workspace carve-up (256B aligned slices)
    char* p = (char*)d_ws;
    auto carve = [&](size_t bytes) {
        char* r = p;
        p += (bytes + 255) & ~(size_t)255;
        return (void*)r;
    };
    int*            hist_g      = (int*)carve((size_t)CHUNKS * 256 * 4);
    int*            histOff     = (int*)carve((size_t)256 * CHUNKS * 4);
    int*            bucketTotal = (int*)carve((size_t)256 * 4);
    int*            bucketBase  = (int*)carve((size_t)256 * 4);
    unsigned*       ebuf        = (unsigned*)carve((size_t)E * 4);
    int*            csr_src     = (int*)carve((size_t)E * 4);
    int*            row_off     = (int*)carve((size_t)(N + 1) * 4);
    float*          dinv        = (float*)carve((size_t)N * 4);
    unsigned short* bufXL       = (unsigned short*)carve((size_t)N * 64 * 2);
    unsigned short* bufXL2      = (unsigned short*)carve((size_t)N * 64 * 2);
    (void)ws_size;

    const int TB = 256;
    // 1. CSR build (bucketed counting sort; no global atomics)
    k_hist<<<CHUNKS, TB, 0, stream>>>(col, E, NBUK, CH, hist_g);
    k_colscan<<<NBUK, TB, 0, stream>>>(hist_g, NBUK, histOff, bucketTotal);
    k_scan_tot<<<1, TB, 0, stream>>>(bucketTotal, NBUK, E, N, bucketBase, row_off);
    k_scatter<<<CHUNKS, TB, 0, stream>>>(row, col, E, NBUK, CH, bucketBase, histOff, ebuf);
    k_bucket<<<NBUK, 512, 0, stream>>>(ebuf, bucketBase, bucketTotal, N,
                                       row_off, dinv, csr_src);

    int gemmGrid = (N + 63) / 64;       // 1563
    int aggGrid  = (N + 31) / 32;       // 3125 (8 nodes/wave x 4 waves)
    // 2. layer 1 GEMM: xl = bf16((x@W1)*dinv)
    k_gemm_mfma<128, false><<<gemmGrid, TB, 0, stream>>>(x, W1, dinv, bufXL, N);
    // 3. fused layer-1 agg + gemm2: xl2 = bf16(dinv*(relu(dinv*Agg(xl)+b1)@W2))
    k_agg_g2<<<aggGrid, TB, 0, stream>>>(bufXL, row_off, csr_src, dinv, b1, W2, bufXL2, N);
    // 4. layer-2 agg + FC + sigmoid
    k_agg_fc<<<aggGrid, TB, 0, stream>>>(bufXL2, row_off, csr_src, dinv, b2, Wfc, bfc, out, N);
}

// Round 7
// 206.773 us; speedup vs baseline: 1.3894x; 1.1789x over previous
//
#include <hip/hip_runtime.h>
#include <math.h>

// ---------------------------------------------------------------------------
// GCN: h1 = relu(Agg(x@W1)+b1); h2 = relu(Agg(h1@W2)+b2); out = sigmoid(h2@Wfc+bfc)
// Agg(xl)[dst] = dinv[dst] * ( sum_{src->dst} xl_s[src] + xl_s[dst] )
//   where xl_s[n] = (x@W)[n] * dinv[n]   (source-side norm folded into GEMM)
// R2-R9: scan / dinv-fold / counting-sort CSR. R10: MFMA GEMMs.
// R11-R14: node-per-slot gather aggs + fused gemm2 (best: 215.7us total).
// R15 deeper chains: NULL. R16 edge-parallel: REGRESS. R17 degree-balance:
// NULL. R18 src-sort: NULL. R19 NT loads: REGRESS (L2 hit loss -> latency up,
// fixed in-flight -> rate down). Model: tput = inflight_cap / avg_latency;
// avg_latency set by L2-miss fraction; table 12.8MB vs 4MB/XCD L2 -> 62% hit.
// R20: fp8 e4m3 layer-1 gather table (HW v_cvt_pk_*_fp8, OCP on gfx950).
//      Table 12.8->6.4MB (L2 residency 31%->62% -> hit ~85%), bytes/edge
//      128->64B. Decode = 4 cvt_pk per 8 feats (less VALU than bf16 unpack).
//      Layer-2 table stays bf16 (bounds accuracy risk; absmax ~+0.002-4).
// ---------------------------------------------------------------------------

typedef __attribute__((ext_vector_type(8))) short bf16x8;
typedef __attribute__((ext_vector_type(4))) float f32x4;
typedef __attribute__((ext_vector_type(2))) float f32x2;

#define CHUNKS 1024

__device__ __forceinline__ unsigned short f2bf(float f) {
    unsigned u = __float_as_uint(f);
    u += 0x7FFFu + ((u >> 16) & 1u);   // round-to-nearest-even
    return (unsigned short)(u >> 16);
}
__device__ __forceinline__ unsigned packbf(float a, float b) {
    return (unsigned)f2bf(a) | ((unsigned)f2bf(b) << 16);
}
// accumulate 8 bf16 (one uint4) into 4 packed f32x2 accumulators
__device__ __forceinline__ void upadd2(uint4 g, f32x2* a) {
    a[0] += (f32x2){__uint_as_float(g.x << 16), __uint_as_float(g.x & 0xFFFF0000u)};
    a[1] += (f32x2){__uint_as_float(g.y << 16), __uint_as_float(g.y & 0xFFFF0000u)};
    a[2] += (f32x2){__uint_as_float(g.z << 16), __uint_as_float(g.z & 0xFFFF0000u)};
    a[3] += (f32x2){__uint_as_float(g.w << 16), __uint_as_float(g.w & 0xFFFF0000u)};
}
// fp8 e4m3 (OCP on gfx950) encode/decode via HW converts
__device__ __forceinline__ unsigned char f2fp8(float f) {
    return (unsigned char)(__builtin_amdgcn_cvt_pk_fp8_f32(f, f, 0u, false) & 0xFFu);
}
// accumulate 8 fp8 (one uint2) into 4 packed f32x2 accumulators
__device__ __forceinline__ void fp8add(uint2 g, f32x2* a) {
    a[0] += __builtin_amdgcn_cvt_pk_f32_fp8((int)g.x, false);
    a[1] += __builtin_amdgcn_cvt_pk_f32_fp8((int)g.x, true);
    a[2] += __builtin_amdgcn_cvt_pk_f32_fp8((int)g.y, false);
    a[3] += __builtin_amdgcn_cvt_pk_f32_fp8((int)g.y, true);
}

// ---- CSR build: bucketed counting sort (no global atomics) ----------------
__global__ __launch_bounds__(256) void k_hist(const int* __restrict__ col, int E,
                                              int NBUK, int CH,
                                              int* __restrict__ hist_g) {
    __shared__ int h[256];
    for (int i = threadIdx.x; i < NBUK; i += 256) h[i] = 0;
    __syncthreads();
    int base = blockIdx.x * CH, hi = min(base + CH, E);
    for (int e = base + (int)threadIdx.x; e < hi; e += 256)
        atomicAdd(&h[col[e] >> 9], 1);
    __syncthreads();
    for (int i = threadIdx.x; i < NBUK; i += 256)
        hist_g[blockIdx.x * NBUK + i] = h[i];
}

__global__ __launch_bounds__(256) void k_colscan(const int* __restrict__ hist_g, int NBUK,
                                                 int* __restrict__ histOff,
                                                 int* __restrict__ bucketTotal) {
    __shared__ int s[256];
    const int b = blockIdx.x, t = threadIdx.x;
    int v[4], sum = 0;
#pragma unroll
    for (int j = 0; j < 4; ++j) {
        v[j] = hist_g[(t * 4 + j) * NBUK + b];
        sum += v[j];
    }
    s[t] = sum;
    __syncthreads();
    for (int off = 1; off < 256; off <<= 1) {
        int u = (t >= off) ? s[t - off] : 0;
        __syncthreads();
        s[t] += u;
        __syncthreads();
    }
    int run = s[t] - sum;
#pragma unroll
    for (int j = 0; j < 4; ++j) {
        histOff[b * CHUNKS + t * 4 + j] = run;
        run += v[j];
    }
    if (t == 255) bucketTotal[b] = run;
}

__global__ __launch_bounds__(256) void k_scan_tot(const int* __restrict__ bucketTotal,
                                                  int NBUK, int E, int N,
                                                  int* __restrict__ bucketBase,
                                                  int* __restrict__ row_off) {
    __shared__ int s[256];
    int t = threadIdx.x;
    int v = (t < NBUK) ? bucketTotal[t] : 0;
    s[t] = v;
    __syncthreads();
    for (int off = 1; off < 256; off <<= 1) {
        int u = (t >= off) ? s[t - off] : 0;
        __syncthreads();
        s[t] += u;
        __syncthreads();
    }
    if (t < NBUK) bucketBase[t] = s[t] - v;
    if (t == 0) row_off[N] = E;
}

__global__ __launch_bounds__(256) void k_scatter(const int* __restrict__ row,
                                                 const int* __restrict__ col, int E,
                                                 int NBUK, int CH,
                                                 const int* __restrict__ bucketBase,
                                                 const int* __restrict__ histOff,
                                                 unsigned* __restrict__ ebuf) {
    __shared__ int cur[256];
    for (int i = threadIdx.x; i < NBUK; i += 256)
        cur[i] = bucketBase[i] + histOff[i * CHUNKS + blockIdx.x];
    __syncthreads();
    int base = blockIdx.x * CH, hi = min(base + CH, E);
    for (int e = base + (int)threadIdx.x; e < hi; e += 256) {
        int d = col[e], src = row[e];
        int b = d >> 9;
        int pos = atomicAdd(&cur[b], 1);             // LDS atomic
        ebuf[pos] = ((unsigned)(d & 511) << 17) | (unsigned)src;
    }
}

__global__ __launch_bounds__(512) void k_bucket(const unsigned* __restrict__ ebuf,
                                                const int* __restrict__ bucketBase,
                                                const int* __restrict__ bucketTotal,
                                                int N,
                                                int* __restrict__ row_off,
                                                float* __restrict__ dinv,
                                                int* __restrict__ csr_src) {
    __shared__ int hc[512], of[512];
    const int bid = blockIdx.x, t = threadIdx.x;
    const int base = bucketBase[bid];
    const int cnt  = bucketTotal[bid];
    hc[t] = 0;
    __syncthreads();
    for (int i = t; i < cnt; i += 512)
        atomicAdd(&hc[ebuf[base + i] >> 17], 1);
    __syncthreads();
    int v = hc[t];
    of[t] = v;
    __syncthreads();
    for (int off = 1; off < 512; off <<= 1) {
        int u = (t >= off) ? of[t - off] : 0;
        __syncthreads();
        of[t] += u;
        __syncthreads();
    }
    int excl = of[t] - v;
    int node = bid * 512 + t;
    if (node < N) {
        row_off[node] = base + excl;
        dinv[node] = rsqrtf((float)(v + 1));   // +1 self loop
    }
    of[t] = excl;
    __syncthreads();
    for (int i = t; i < cnt; i += 512) {
        unsigned e = ebuf[base + i];
        int dl = (int)(e >> 17), src = (int)(e & 0x1FFFFu);
        int pos = atomicAdd(&of[dl], 1);       // LDS atomic
        csr_src[base + pos] = src;
    }
}

// ---- MFMA GEMM layer 1: xl = fp8((x@W1)*dinv) -----------------------------
template <int K>
__global__ __launch_bounds__(256) void k_gemm_mfma(const float* __restrict__ xf,
                                                   const float* __restrict__ W,
                                                   const float* __restrict__ dinv,
                                                   unsigned char* __restrict__ out,
                                                   int N) {
    constexpr int KS = K + 8;
    __shared__ short sX[64 * KS];
    __shared__ short sW[64 * KS];
    const int tid = threadIdx.x;
    const int wv = tid >> 6, lane = tid & 63;
    const int q = lane >> 4, m = lane & 15;
    const int nb = blockIdx.x * 64;

    for (int i = tid; i < K * 64; i += 256) {
        int k = i >> 6, c = i & 63;
        sW[c * KS + k] = (short)f2bf(W[i]);
    }
    for (int i = tid; i < 64 * (K / 8); i += 256) {
        int r = i / (K / 8), c8 = (i % (K / 8)) * 8;
        int node = nb + r;
        uint4 v = make_uint4(0u, 0u, 0u, 0u);
        if (node < N) {
            float4 lo = *(const float4*)(xf + (size_t)node * K + c8);
            float4 hi = *(const float4*)(xf + (size_t)node * K + c8 + 4);
            v.x = packbf(lo.x, lo.y);
            v.y = packbf(lo.z, lo.w);
            v.z = packbf(hi.x, hi.y);
            v.w = packbf(hi.z, hi.w);
        }
        *(uint4*)(&sX[r * KS + c8]) = v;
    }
    __syncthreads();

    f32x4 acc[4] = {};
    const short* aRow = &sX[(wv * 16 + m) * KS + q * 8];
#pragma unroll
    for (int k0 = 0; k0 < K; k0 += 32) {
        bf16x8 a = *(const bf16x8*)(aRow + k0);
#pragma unroll
        for (int ft = 0; ft < 4; ++ft) {
            bf16x8 b = *(const bf16x8*)(&sW[(ft * 16 + m) * KS + k0 + q * 8]);
            acc[ft] = __builtin_amdgcn_mfma_f32_16x16x32_bf16(a, b, acc[ft], 0, 0, 0);
        }
    }
#pragma unroll
    for (int r = 0; r < 4; ++r) {
        int node = nb + wv * 16 + q * 4 + r;
        if (node < N) {
            float di = dinv[node];
#pragma unroll
            for (int ft = 0; ft < 4; ++ft)
                out[(size_t)node * 64 + ft * 16 + m] = f2fp8(acc[ft][r] * di);
        }
    }
}

// ---- fused layer-1 agg + gemm2 (fp8 gather table) -------------------------
// Phase A (gather): 8 nodes/wave, slot s=lane>>3 owns node, octet o=lane&7
// owns feats [8o,8o+8) = 8 fp8 bytes; 4-way prefetched gather chains;
// self = virtual edge. Phase B: h1 rows bf16 -> LDS A-tile (rows 8-15 zero),
// 8 mfma_16x16x32_bf16 vs LDS W2^T, dinv -> bf16 xl2.
__global__ __launch_bounds__(256) void k_agg_g2(const unsigned char* __restrict__ xl,
                                                const int* __restrict__ row_off,
                                                const int* __restrict__ csr_src,
                                                const float* __restrict__ dinv,
                                                const float* __restrict__ bias,
                                                const float* __restrict__ W2,
                                                unsigned short* __restrict__ out, int N) {
    constexpr int KS = 72;               // 64 + 8 pad (bf16 elems)
    __shared__ short sH[4 * 16 * KS];    // per-wave 16x64 A-tiles (9KB)
    __shared__ short sW2[64 * KS];       // W2^T bf16 (9KB)
    const int tid = threadIdx.x;
    const int wv = tid >> 6, lane = tid & 63;
    const int s = lane >> 3, o = lane & 7;
    const int q = lane >> 4, m = lane & 15;

    // stage W2 transposed bf16: sW2[n*KS+k] = bf16(W2[k*64+n])
    for (int i = tid; i < 64 * 64; i += 256) {
        int k = i >> 6, n = i & 63;
        sW2[n * KS + k] = (short)f2bf(W2[i]);
    }
    // zero this wave's A-tile rows 8-15 (never written by gather phase)
    short* myH = &sH[wv * 16 * KS];
    for (int i = lane; i < 8 * KS / 4; i += 64)
        ((unsigned long long*)(myH + 8 * KS))[i] = 0ull;
    __syncthreads();                     // sW2 visible to all waves

    const int base8 = (blockIdx.x * 4 + wv) * 8;
    int node = base8 + s;
    const bool active = node < N;
    node = min(node, N - 1);
    const int beg = row_off[node];
    const int deg = row_off[node + 1] - beg;
    const int cnt = active ? deg + 1 : 0;
    int mx = cnt;
    mx = max(mx, __shfl_xor(mx, 8, 64));
    mx = max(mx, __shfl_xor(mx, 16, 64));
    mx = max(mx, __shfl_xor(mx, 32, 64));
    const char* xlb = (const char*)xl;
    const unsigned loff = (unsigned)(o << 3);          // 8B per octet
    f32x2 acc0[4] = {}, acc1[4] = {};
    int idx[4];
#pragma unroll
    for (int j = 0; j < 4; ++j) idx[j] = (j < deg) ? csr_src[beg + j] : node;
    for (int it = 0; it < mx; it += 4) {
        int c[4];
        bool v[4];
#pragma unroll
        for (int j = 0; j < 4; ++j) {
            c[j] = idx[j];
            v[j] = (it + j) < cnt;
            idx[j] = (it + 4 + j < deg) ? csr_src[beg + it + 4 + j] : node;
        }
        uint2 g0 = *(const uint2*)(xlb + (((unsigned)c[0] << 6) | loff));
        uint2 g1 = *(const uint2*)(xlb + (((unsigned)c[1] << 6) | loff));
        uint2 g2 = *(const uint2*)(xlb + (((unsigned)c[2] << 6) | loff));
        uint2 g3 = *(const uint2*)(xlb + (((unsigned)c[3] << 6) | loff));
        if (!v[0]) g0 = make_uint2(0u, 0u);
        if (!v[1]) g1 = make_uint2(0u, 0u);
        if (!v[2]) g2 = make_uint2(0u, 0u);
        if (!v[3]) g3 = make_uint2(0u, 0u);
        fp8add(g0, acc0);
        fp8add(g1, acc1);
        fp8add(g2, acc0);
        fp8add(g3, acc1);
    }
#pragma unroll
    for (int j = 0; j < 4; ++j) acc0[j] += acc1[j];
    // h1 row -> LDS A-tile (bf16), row = slot s
    {
        float di = dinv[node];
        float4 blo = *(const float4*)(bias + o * 8);
        float4 bhi = *(const float4*)(bias + o * 8 + 4);
        uint4 h;
        h.x = packbf(fmaxf(acc0[0].x * di + blo.x, 0.f), fmaxf(acc0[0].y * di + blo.y, 0.f));
        h.y = packbf(fmaxf(acc0[1].x * di + blo.z, 0.f), fmaxf(acc0[1].y * di + blo.w, 0.f));
        h.z = packbf(fmaxf(acc0[2].x * di + bhi.x, 0.f), fmaxf(acc0[2].y * di + bhi.y, 0.f));
        h.w = packbf(fmaxf(acc0[3].x * di + bhi.z, 0.f), fmaxf(acc0[3].y * di + bhi.w, 0.f));
        *(uint4*)(myH + s * KS + o * 8) = h;     // same-wave LDS, no barrier
    }
    // gemm2: 8 MFMA (4 feat-tiles x K=64)
    f32x4 accm[4] = {};
#pragma unroll
    for (int k0 = 0; k0 < 64; k0 += 32) {
        bf16x8 a = *(const bf16x8*)(myH + m * KS + q * 8 + k0);
#pragma unroll
        for (int ft = 0; ft < 4; ++ft) {
            bf16x8 b = *(const bf16x8*)(&sW2[(ft * 16 + m) * KS + k0 + q * 8]);
            accm[ft] = __builtin_amdgcn_mfma_f32_16x16x32_bf16(a, b, accm[ft], 0, 0, 0);
        }
    }
    if (q < 2) {                          // valid rows 0..7
#pragma unroll
        for (int r = 0; r < 4; ++r) {
            int node2 = base8 + q * 4 + r;
            if (node2 < N) {
                float di2 = dinv[node2];
#pragma unroll
                for (int ft = 0; ft < 4; ++ft)
                    out[(size_t)node2 * 64 + ft * 16 + m] = f2bf(accm[ft][r] * di2);
            }
        }
    }
}

// Layer-2 agg + final FC + sigmoid (bf16 table, 4-way chains, R14 form).
__global__ __launch_bounds__(256) void k_agg_fc(const unsigned short* __restrict__ xl,
                                                const int* __restrict__ row_off,
                                                const int* __restrict__ csr_src,
                                                const float* __restrict__ dinv,
                                                const float* __restrict__ bias,
                                                const float* __restrict__ Wfc,
                                                const float* __restrict__ bfc,
                                                float* __restrict__ out, int N) {
    const int wave = threadIdx.x >> 6, lane = threadIdx.x & 63;
    const int s = lane >> 3, o = lane & 7;
    int node = (blockIdx.x * 4 + wave) * 8 + s;
    const bool active = node < N;
    node = min(node, N - 1);
    const int beg = row_off[node];
    const int deg = row_off[node + 1] - beg;
    const int cnt = active ? deg + 1 : 0;
    int mx = cnt;
    mx = max(mx, __shfl_xor(mx, 8, 64));
    mx = max(mx, __shfl_xor(mx, 16, 64));
    mx = max(mx, __shfl_xor(mx, 32, 64));
    const char* xlb = (const char*)xl;
    const unsigned loff = (unsigned)(o << 4);
    f32x2 acc0[4] = {}, acc1[4] = {};
    int idx[4];
#pragma unroll
    for (int j = 0; j < 4; ++j) idx[j] = (j < deg) ? csr_src[beg + j] : node;
    for (int it = 0; it < mx; it += 4) {
        int c[4];
        bool v[4];
#pragma unroll
        for (int j = 0; j < 4; ++j) {
            c[j] = idx[j];
            v[j] = (it + j) < cnt;
            idx[j] = (it + 4 + j < deg) ? csr_src[beg + it + 4 + j] : node;
        }
        uint4 g0 = *(const uint4*)(xlb + (((unsigned)c[0] << 7) | loff));
        uint4 g1 = *(const uint4*)(xlb + (((unsigned)c[1] << 7) | loff));
        uint4 g2 = *(const uint4*)(xlb + (((unsigned)c[2] << 7) | loff));
        uint4 g3 = *(const uint4*)(xlb + (((unsigned)c[3] << 7) | loff));
        if (!v[0]) g0 = make_uint4(0u, 0u, 0u, 0u);
        if (!v[1]) g1 = make_uint4(0u, 0u, 0u, 0u);
        if (!v[2]) g2 = make_uint4(0u, 0u, 0u, 0u);
        if (!v[3]) g3 = make_uint4(0u, 0u, 0u, 0u);
        upadd2(g0, acc0);
        upadd2(g1, acc1);
        upadd2(g2, acc0);
        upadd2(g3, acc1);
    }
#pragma unroll
    for (int j = 0; j < 4; ++j) acc0[j] += acc1[j];
    const float di = dinv[node];
    float4 blo = *(const float4*)(bias + o * 8);
    float4 bhi = *(const float4*)(bias + o * 8 + 4);
    float4 wlo = *(const float4*)(Wfc + o * 8);
    float4 whi = *(const float4*)(Wfc + o * 8 + 4);
    float v = 0.f;
    v += fmaxf(acc0[0].x * di + blo.x, 0.f) * wlo.x;
    v += fmaxf(acc0[0].y * di + blo.y, 0.f) * wlo.y;
    v += fmaxf(acc0[1].x * di + blo.z, 0.f) * wlo.z;
    v += fmaxf(acc0[1].y * di + blo.w, 0.f) * wlo.w;
    v += fmaxf(acc0[2].x * di + bhi.x, 0.f) * whi.x;
    v += fmaxf(acc0[2].y * di + bhi.y, 0.f) * whi.y;
    v += fmaxf(acc0[3].x * di + bhi.z, 0.f) * whi.z;
    v += fmaxf(acc0[3].y * di + bhi.w, 0.f) * whi.w;
    v += __shfl_xor(v, 1, 64);
    v += __shfl_xor(v, 2, 64);
    v += __shfl_xor(v, 4, 64);
    if (active && o == 0) out[node] = 1.f / (1.f + expf(-(v + bfc[0])));
}

extern "C" void kernel_launch(void* const* d_in, const int* in_sizes, int n_in,
                              void* d_out, int out_size, void* d_ws, size_t ws_size,
                              hipStream_t stream) {
    const float* x   = (const float*)d_in[0];
    const int*   ei  = (const int*)d_in[1];   // [2, E]: row then col
    const float* W1  = (const float*)d_in[2];
    const float* b1  = (const float*)d_in[3];
    const float* W2  = (const float*)d_in[4];
    const float* b2  = (const float*)d_in[5];
    const float* Wfc = (const float*)d_in[6];
    const float* bfc = (const float*)d_in[7];
    float* out = (float*)d_out;

    const int H = in_sizes[3];          // 64
    const int D = in_sizes[2] / H;      // 128
    const int N = in_sizes[0] / D;      // 100000
    const int E = in_sizes[1] / 2;      // 1600000
    const int* row = ei;
    const int* col = ei + E;
    const int NBUK = (N + 511) >> 9;    // 196 buckets of 512 nodes
    const int CH   = (E + CHUNKS - 1) / CHUNKS;

    // Workspace carve-up (256B aligned slices)
    char* p = (char*)d_ws;
    auto carve = [&](size_t bytes) {
        char* r = p;
        p += (bytes + 255) & ~(size_t)255;
        return (void*)r;
    };
    int*            hist_g      = (int*)carve((size_t)CHUNKS * 256 * 4);
    int*            histOff     = (int*)carve((size_t)256 * CHUNKS * 4);
    int*            bucketTotal = (int*)carve((size_t)256 * 4);
    int*            bucketBase  = (int*)carve((size_t)256 * 4);
    unsigned*       ebuf        = (unsigned*)carve((size_t)E * 4);
    int*            csr_src     = (int*)carve((size_t)E * 4);
    int*            row_off     = (int*)carve((size_t)(N + 1) * 4);
    float*          dinv        = (float*)carve((size_t)N * 4);
    unsigned char*  bufXL8      = (unsigned char*)carve((size_t)N * 64);
    unsigned short* bufXL2      = (unsigned short*)carve((size_t)N * 64 * 2);
    (void)ws_size;

    const int TB = 256;
    // 1. CSR build (bucketed counting sort; no global atomics)
    k_hist<<<CHUNKS, TB, 0, stream>>>(col, E, NBUK, CH, hist_g);
    k_colscan<<<NBUK, TB, 0, stream>>>(hist_g, NBUK, histOff, bucketTotal);
    k_scan_tot<<<1, TB, 0, stream>>>(bucketTotal, NBUK, E, N, bucketBase, row_off);
    k_scatter<<<CHUNKS, TB, 0, stream>>>(row, col, E, NBUK, CH, bucketBase, histOff, ebuf);
    k_bucket<<<NBUK, 512, 0, stream>>>(ebuf, bucketBase, bucketTotal, N,
                                       row_off, dinv, csr_src);

    int gemmGrid = (N + 63) / 64;       // 1563
    int aggGrid  = (N + 31) / 32;       // 3125 (8 nodes/wave x 4 waves)
    // 2. layer 1 GEMM: xl = fp8((x@W1)*dinv)
    k_gemm_mfma<128><<<gemmGrid, TB, 0, stream>>>(x, W1, dinv, bufXL8, N);
    // 3. fused layer-1 agg + gemm2: xl2 = bf16(dinv*(relu(dinv*Agg(xl)+b1)@W2))
    k_agg_g2<<<aggGrid, TB, 0, stream>>>(bufXL8, row_off, csr_src, dinv, b1, W2, bufXL2, N);
    // 4. layer-2 agg + FC + sigmoid
    k_agg_fc<<<aggGrid, TB, 0, stream>>>(bufXL2, row_off, csr_src, dinv, b2, Wfc, bfc, out, N);
}

// Round 8
// 203.886 us; speedup vs baseline: 1.4091x; 1.0142x over previous
//
#include <hip/hip_runtime.h>
#include <math.h>

// ---------------------------------------------------------------------------
// GCN: h1 = relu(Agg(x@W1)+b1); h2 = relu(Agg(h1@W2)+b2); out = sigmoid(h2@Wfc+bfc)
// Agg(xl)[dst] = dinv[dst] * ( sum_{src->dst} xl_s[src] + xl_s[dst] )
//   where xl_s[n] = (x@W)[n] * dinv[n]   (source-side norm folded into GEMM)
// R2-R14: CSR counting sort + MFMA GEMMs + node-per-slot gather aggs + fused
//         gemm2 (215.7us). R15-R19: depth/shape/balance/sort/NT all NULL or
//         regress => tput = inflight_cap / avg_latency, avg_latency set by
//         L2-miss fraction of the gather table.
// R20: fp8 e4m3 layer-1 gather table (12.8->6.4MB, 128->64B/row) -> 206.8us,
//      agg_g2 ~41.5->~32us. Mechanism CONFIRMED: shrink table -> L2 hit up.
// R21: same treatment for layer-2: xl2 stored fp8 e4m3 (gemm2 epilogue in
//      k_agg_g2 writes fp8; k_agg_fc gathers uint2 + HW cvt). absmax budget:
//      one more e4m3 quant ahead of mean-agg + FC + sigmoid (~+0.002-4).
// ---------------------------------------------------------------------------

typedef __attribute__((ext_vector_type(8))) short bf16x8;
typedef __attribute__((ext_vector_type(4))) float f32x4;
typedef __attribute__((ext_vector_type(2))) float f32x2;

#define CHUNKS 1024

__device__ __forceinline__ unsigned short f2bf(float f) {
    unsigned u = __float_as_uint(f);
    u += 0x7FFFu + ((u >> 16) & 1u);   // round-to-nearest-even
    return (unsigned short)(u >> 16);
}
__device__ __forceinline__ unsigned packbf(float a, float b) {
    return (unsigned)f2bf(a) | ((unsigned)f2bf(b) << 16);
}
// accumulate 8 bf16 (one uint4) into 4 packed f32x2 accumulators
__device__ __forceinline__ void upadd2(uint4 g, f32x2* a) {
    a[0] += (f32x2){__uint_as_float(g.x << 16), __uint_as_float(g.x & 0xFFFF0000u)};
    a[1] += (f32x2){__uint_as_float(g.y << 16), __uint_as_float(g.y & 0xFFFF0000u)};
    a[2] += (f32x2){__uint_as_float(g.z << 16), __uint_as_float(g.z & 0xFFFF0000u)};
    a[3] += (f32x2){__uint_as_float(g.w << 16), __uint_as_float(g.w & 0xFFFF0000u)};
}
// fp8 e4m3 (OCP on gfx950) encode/decode via HW converts
__device__ __forceinline__ unsigned char f2fp8(float f) {
    return (unsigned char)(__builtin_amdgcn_cvt_pk_fp8_f32(f, f, 0u, false) & 0xFFu);
}
// accumulate 8 fp8 (one uint2) into 4 packed f32x2 accumulators
__device__ __forceinline__ void fp8add(uint2 g, f32x2* a) {
    a[0] += __builtin_amdgcn_cvt_pk_f32_fp8((int)g.x, false);
    a[1] += __builtin_amdgcn_cvt_pk_f32_fp8((int)g.x, true);
    a[2] += __builtin_amdgcn_cvt_pk_f32_fp8((int)g.y, false);
    a[3] += __builtin_amdgcn_cvt_pk_f32_fp8((int)g.y, true);
}

// ---- CSR build: bucketed counting sort (no global atomics) ----------------
__global__ __launch_bounds__(256) void k_hist(const int* __restrict__ col, int E,
                                              int NBUK, int CH,
                                              int* __restrict__ hist_g) {
    __shared__ int h[256];
    for (int i = threadIdx.x; i < NBUK; i += 256) h[i] = 0;
    __syncthreads();
    int base = blockIdx.x * CH, hi = min(base + CH, E);
    for (int e = base + (int)threadIdx.x; e < hi; e += 256)
        atomicAdd(&h[col[e] >> 9], 1);
    __syncthreads();
    for (int i = threadIdx.x; i < NBUK; i += 256)
        hist_g[blockIdx.x * NBUK + i] = h[i];
}

__global__ __launch_bounds__(256) void k_colscan(const int* __restrict__ hist_g, int NBUK,
                                                 int* __restrict__ histOff,
                                                 int* __restrict__ bucketTotal) {
    __shared__ int s[256];
    const int b = blockIdx.x, t = threadIdx.x;
    int v[4], sum = 0;
#pragma unroll
    for (int j = 0; j < 4; ++j) {
        v[j] = hist_g[(t * 4 + j) * NBUK + b];
        sum += v[j];
    }
    s[t] = sum;
    __syncthreads();
    for (int off = 1; off < 256; off <<= 1) {
        int u = (t >= off) ? s[t - off] : 0;
        __syncthreads();
        s[t] += u;
        __syncthreads();
    }
    int run = s[t] - sum;
#pragma unroll
    for (int j = 0; j < 4; ++j) {
        histOff[b * CHUNKS + t * 4 + j] = run;
        run += v[j];
    }
    if (t == 255) bucketTotal[b] = run;
}

__global__ __launch_bounds__(256) void k_scan_tot(const int* __restrict__ bucketTotal,
                                                  int NBUK, int E, int N,
                                                  int* __restrict__ bucketBase,
                                                  int* __restrict__ row_off) {
    __shared__ int s[256];
    int t = threadIdx.x;
    int v = (t < NBUK) ? bucketTotal[t] : 0;
    s[t] = v;
    __syncthreads();
    for (int off = 1; off < 256; off <<= 1) {
        int u = (t >= off) ? s[t - off] : 0;
        __syncthreads();
        s[t] += u;
        __syncthreads();
    }
    if (t < NBUK) bucketBase[t] = s[t] - v;
    if (t == 0) row_off[N] = E;
}

__global__ __launch_bounds__(256) void k_scatter(const int* __restrict__ row,
                                                 const int* __restrict__ col, int E,
                                                 int NBUK, int CH,
                                                 const int* __restrict__ bucketBase,
                                                 const int* __restrict__ histOff,
                                                 unsigned* __restrict__ ebuf) {
    __shared__ int cur[256];
    for (int i = threadIdx.x; i < NBUK; i += 256)
        cur[i] = bucketBase[i] + histOff[i * CHUNKS + blockIdx.x];
    __syncthreads();
    int base = blockIdx.x * CH, hi = min(base + CH, E);
    for (int e = base + (int)threadIdx.x; e < hi; e += 256) {
        int d = col[e], src = row[e];
        int b = d >> 9;
        int pos = atomicAdd(&cur[b], 1);             // LDS atomic
        ebuf[pos] = ((unsigned)(d & 511) << 17) | (unsigned)src;
    }
}

__global__ __launch_bounds__(512) void k_bucket(const unsigned* __restrict__ ebuf,
                                                const int* __restrict__ bucketBase,
                                                const int* __restrict__ bucketTotal,
                                                int N,
                                                int* __restrict__ row_off,
                                                float* __restrict__ dinv,
                                                int* __restrict__ csr_src) {
    __shared__ int hc[512], of[512];
    const int bid = blockIdx.x, t = threadIdx.x;
    const int base = bucketBase[bid];
    const int cnt  = bucketTotal[bid];
    hc[t] = 0;
    __syncthreads();
    for (int i = t; i < cnt; i += 512)
        atomicAdd(&hc[ebuf[base + i] >> 17], 1);
    __syncthreads();
    int v = hc[t];
    of[t] = v;
    __syncthreads();
    for (int off = 1; off < 512; off <<= 1) {
        int u = (t >= off) ? of[t - off] : 0;
        __syncthreads();
        of[t] += u;
        __syncthreads();
    }
    int excl = of[t] - v;
    int node = bid * 512 + t;
    if (node < N) {
        row_off[node] = base + excl;
        dinv[node] = rsqrtf((float)(v + 1));   // +1 self loop
    }
    of[t] = excl;
    __syncthreads();
    for (int i = t; i < cnt; i += 512) {
        unsigned e = ebuf[base + i];
        int dl = (int)(e >> 17), src = (int)(e & 0x1FFFFu);
        int pos = atomicAdd(&of[dl], 1);       // LDS atomic
        csr_src[base + pos] = src;
    }
}

// ---- MFMA GEMM layer 1: xl = fp8((x@W1)*dinv) -----------------------------
template <int K>
__global__ __launch_bounds__(256) void k_gemm_mfma(const float* __restrict__ xf,
                                                   const float* __restrict__ W,
                                                   const float* __restrict__ dinv,
                                                   unsigned char* __restrict__ out,
                                                   int N) {
    constexpr int KS = K + 8;
    __shared__ short sX[64 * KS];
    __shared__ short sW[64 * KS];
    const int tid = threadIdx.x;
    const int wv = tid >> 6, lane = tid & 63;
    const int q = lane >> 4, m = lane & 15;
    const int nb = blockIdx.x * 64;

    for (int i = tid; i < K * 64; i += 256) {
        int k = i >> 6, c = i & 63;
        sW[c * KS + k] = (short)f2bf(W[i]);
    }
    for (int i = tid; i < 64 * (K / 8); i += 256) {
        int r = i / (K / 8), c8 = (i % (K / 8)) * 8;
        int node = nb + r;
        uint4 v = make_uint4(0u, 0u, 0u, 0u);
        if (node < N) {
            float4 lo = *(const float4*)(xf + (size_t)node * K + c8);
            float4 hi = *(const float4*)(xf + (size_t)node * K + c8 + 4);
            v.x = packbf(lo.x, lo.y);
            v.y = packbf(lo.z, lo.w);
            v.z = packbf(hi.x, hi.y);
            v.w = packbf(hi.z, hi.w);
        }
        *(uint4*)(&sX[r * KS + c8]) = v;
    }
    __syncthreads();

    f32x4 acc[4] = {};
    const short* aRow = &sX[(wv * 16 + m) * KS + q * 8];
#pragma unroll
    for (int k0 = 0; k0 < K; k0 += 32) {
        bf16x8 a = *(const bf16x8*)(aRow + k0);
#pragma unroll
        for (int ft = 0; ft < 4; ++ft) {
            bf16x8 b = *(const bf16x8*)(&sW[(ft * 16 + m) * KS + k0 + q * 8]);
            acc[ft] = __builtin_amdgcn_mfma_f32_16x16x32_bf16(a, b, acc[ft], 0, 0, 0);
        }
    }
#pragma unroll
    for (int r = 0; r < 4; ++r) {
        int node = nb + wv * 16 + q * 4 + r;
        if (node < N) {
            float di = dinv[node];
#pragma unroll
            for (int ft = 0; ft < 4; ++ft)
                out[(size_t)node * 64 + ft * 16 + m] = f2fp8(acc[ft][r] * di);
        }
    }
}

// ---- fused layer-1 agg + gemm2 (fp8 gather table, fp8 xl2 output) ---------
// Phase A (gather): 8 nodes/wave, slot s=lane>>3 owns node, octet o=lane&7
// owns feats [8o,8o+8) = 8 fp8 bytes; 4-way prefetched gather chains;
// self = virtual edge. Phase B: h1 rows bf16 -> LDS A-tile (rows 8-15 zero),
// 8 mfma_16x16x32_bf16 vs LDS W2^T, dinv -> fp8 xl2.
__global__ __launch_bounds__(256) void k_agg_g2(const unsigned char* __restrict__ xl,
                                                const int* __restrict__ row_off,
                                                const int* __restrict__ csr_src,
                                                const float* __restrict__ dinv,
                                                const float* __restrict__ bias,
                                                const float* __restrict__ W2,
                                                unsigned char* __restrict__ out, int N) {
    constexpr int KS = 72;               // 64 + 8 pad (bf16 elems)
    __shared__ short sH[4 * 16 * KS];    // per-wave 16x64 A-tiles (9KB)
    __shared__ short sW2[64 * KS];       // W2^T bf16 (9KB)
    const int tid = threadIdx.x;
    const int wv = tid >> 6, lane = tid & 63;
    const int s = lane >> 3, o = lane & 7;
    const int q = lane >> 4, m = lane & 15;

    // stage W2 transposed bf16: sW2[n*KS+k] = bf16(W2[k*64+n])
    for (int i = tid; i < 64 * 64; i += 256) {
        int k = i >> 6, n = i & 63;
        sW2[n * KS + k] = (short)f2bf(W2[i]);
    }
    // zero this wave's A-tile rows 8-15 (never written by gather phase)
    short* myH = &sH[wv * 16 * KS];
    for (int i = lane; i < 8 * KS / 4; i += 64)
        ((unsigned long long*)(myH + 8 * KS))[i] = 0ull;
    __syncthreads();                     // sW2 visible to all waves

    const int base8 = (blockIdx.x * 4 + wv) * 8;
    int node = base8 + s;
    const bool active = node < N;
    node = min(node, N - 1);
    const int beg = row_off[node];
    const int deg = row_off[node + 1] - beg;
    const int cnt = active ? deg + 1 : 0;
    int mx = cnt;
    mx = max(mx, __shfl_xor(mx, 8, 64));
    mx = max(mx, __shfl_xor(mx, 16, 64));
    mx = max(mx, __shfl_xor(mx, 32, 64));
    const char* xlb = (const char*)xl;
    const unsigned loff = (unsigned)(o << 3);          // 8B per octet
    f32x2 acc0[4] = {}, acc1[4] = {};
    int idx[4];
#pragma unroll
    for (int j = 0; j < 4; ++j) idx[j] = (j < deg) ? csr_src[beg + j] : node;
    for (int it = 0; it < mx; it += 4) {
        int c[4];
        bool v[4];
#pragma unroll
        for (int j = 0; j < 4; ++j) {
            c[j] = idx[j];
            v[j] = (it + j) < cnt;
            idx[j] = (it + 4 + j < deg) ? csr_src[beg + it + 4 + j] : node;
        }
        uint2 g0 = *(const uint2*)(xlb + (((unsigned)c[0] << 6) | loff));
        uint2 g1 = *(const uint2*)(xlb + (((unsigned)c[1] << 6) | loff));
        uint2 g2 = *(const uint2*)(xlb + (((unsigned)c[2] << 6) | loff));
        uint2 g3 = *(const uint2*)(xlb + (((unsigned)c[3] << 6) | loff));
        if (!v[0]) g0 = make_uint2(0u, 0u);
        if (!v[1]) g1 = make_uint2(0u, 0u);
        if (!v[2]) g2 = make_uint2(0u, 0u);
        if (!v[3]) g3 = make_uint2(0u, 0u);
        fp8add(g0, acc0);
        fp8add(g1, acc1);
        fp8add(g2, acc0);
        fp8add(g3, acc1);
    }
#pragma unroll
    for (int j = 0; j < 4; ++j) acc0[j] += acc1[j];
    // h1 row -> LDS A-tile (bf16), row = slot s
    {
        float di = dinv[node];
        float4 blo = *(const float4*)(bias + o * 8);
        float4 bhi = *(const float4*)(bias + o * 8 + 4);
        uint4 h;
        h.x = packbf(fmaxf(acc0[0].x * di + blo.x, 0.f), fmaxf(acc0[0].y * di + blo.y, 0.f));
        h.y = packbf(fmaxf(acc0[1].x * di + blo.z, 0.f), fmaxf(acc0[1].y * di + blo.w, 0.f));
        h.z = packbf(fmaxf(acc0[2].x * di + bhi.x, 0.f), fmaxf(acc0[2].y * di + bhi.y, 0.f));
        h.w = packbf(fmaxf(acc0[3].x * di + bhi.z, 0.f), fmaxf(acc0[3].y * di + bhi.w, 0.f));
        *(uint4*)(myH + s * KS + o * 8) = h;     // same-wave LDS, no barrier
    }
    // gemm2: 8 MFMA (4 feat-tiles x K=64)
    f32x4 accm[4] = {};
#pragma unroll
    for (int k0 = 0; k0 < 64; k0 += 32) {
        bf16x8 a = *(const bf16x8*)(myH + m * KS + q * 8 + k0);
#pragma unroll
        for (int ft = 0; ft < 4; ++ft) {
            bf16x8 b = *(const bf16x8*)(&sW2[(ft * 16 + m) * KS + k0 + q * 8]);
            accm[ft] = __builtin_amdgcn_mfma_f32_16x16x32_bf16(a, b, accm[ft], 0, 0, 0);
        }
    }
    if (q < 2) {                          // valid rows 0..7
#pragma unroll
        for (int r = 0; r < 4; ++r) {
            int node2 = base8 + q * 4 + r;
            if (node2 < N) {
                float di2 = dinv[node2];
#pragma unroll
                for (int ft = 0; ft < 4; ++ft)
                    out[(size_t)node2 * 64 + ft * 16 + m] = f2fp8(accm[ft][r] * di2);
            }
        }
    }
}

// Layer-2 agg + final FC + sigmoid (fp8 table, 4-way chains).
__global__ __launch_bounds__(256) void k_agg_fc(const unsigned char* __restrict__ xl,
                                                const int* __restrict__ row_off,
                                                const int* __restrict__ csr_src,
                                                const float* __restrict__ dinv,
                                                const float* __restrict__ bias,
                                                const float* __restrict__ Wfc,
                                                const float* __restrict__ bfc,
                                                float* __restrict__ out, int N) {
    const int wave = threadIdx.x >> 6, lane = threadIdx.x & 63;
    const int s = lane >> 3, o = lane & 7;
    int node = (blockIdx.x * 4 + wave) * 8 + s;
    const bool active = node < N;
    node = min(node, N - 1);
    const int beg = row_off[node];
    const int deg = row_off[node + 1] - beg;
    const int cnt = active ? deg + 1 : 0;
    int mx = cnt;
    mx = max(mx, __shfl_xor(mx, 8, 64));
    mx = max(mx, __shfl_xor(mx, 16, 64));
    mx = max(mx, __shfl_xor(mx, 32, 64));
    const char* xlb = (const char*)xl;
    const unsigned loff = (unsigned)(o << 3);          // 8B per octet
    f32x2 acc0[4] = {}, acc1[4] = {};
    int idx[4];
#pragma unroll
    for (int j = 0; j < 4; ++j) idx[j] = (j < deg) ? csr_src[beg + j] : node;
    for (int it = 0; it < mx; it += 4) {
        int c[4];
        bool v[4];
#pragma unroll
        for (int j = 0; j < 4; ++j) {
            c[j] = idx[j];
            v[j] = (it + j) < cnt;
            idx[j] = (it + 4 + j < deg) ? csr_src[beg + it + 4 + j] : node;
        }
        uint2 g0 = *(const uint2*)(xlb + (((unsigned)c[0] << 6) | loff));
        uint2 g1 = *(const uint2*)(xlb + (((unsigned)c[1] << 6) | loff));
        uint2 g2 = *(const uint2*)(xlb + (((unsigned)c[2] << 6) | loff));
        uint2 g3 = *(const uint2*)(xlb + (((unsigned)c[3] << 6) | loff));
        if (!v[0]) g0 = make_uint2(0u, 0u);
        if (!v[1]) g1 = make_uint2(0u, 0u);
        if (!v[2]) g2 = make_uint2(0u, 0u);
        if (!v[3]) g3 = make_uint2(0u, 0u);
        fp8add(g0, acc0);
        fp8add(g1, acc1);
        fp8add(g2, acc0);
        fp8add(g3, acc1);
    }
#pragma unroll
    for (int j = 0; j < 4; ++j) acc0[j] += acc1[j];
    const float di = dinv[node];
    float4 blo = *(const float4*)(bias + o * 8);
    float4 bhi = *(const float4*)(bias + o * 8 + 4);
    float4 wlo = *(const float4*)(Wfc + o * 8);
    float4 whi = *(const float4*)(Wfc + o * 8 + 4);
    float v = 0.f;
    v += fmaxf(acc0[0].x * di + blo.x, 0.f) * wlo.x;
    v += fmaxf(acc0[0].y * di + blo.y, 0.f) * wlo.y;
    v += fmaxf(acc0[1].x * di + blo.z, 0.f) * wlo.z;
    v += fmaxf(acc0[1].y * di + blo.w, 0.f) * wlo.w;
    v += fmaxf(acc0[2].x * di + bhi.x, 0.f) * whi.x;
    v += fmaxf(acc0[2].y * di + bhi.y, 0.f) * whi.y;
    v += fmaxf(acc0[3].x * di + bhi.z, 0.f) * whi.z;
    v += fmaxf(acc0[3].y * di + bhi.w, 0.f) * whi.w;
    v += __shfl_xor(v, 1, 64);
    v += __shfl_xor(v, 2, 64);
    v += __shfl_xor(v, 4, 64);
    if (active && o == 0) out[node] = 1.f / (1.f + expf(-(v + bfc[0])));
}

extern "C" void kernel_launch(void* const* d_in, const int* in_sizes, int n_in,
                              void* d_out, int out_size, void* d_ws, size_t ws_size,
                              hipStream_t stream) {
    const float* x   = (const float*)d_in[0];
    const int*   ei  = (const int*)d_in[1];   // [2, E]: row then col
    const float* W1  = (const float*)d_in[2];
    const float* b1  = (const float*)d_in[3];
    const float* W2  = (const float*)d_in[4];
    const float* b2  = (const float*)d_in[5];
    const float* Wfc = (const float*)d_in[6];
    const float* bfc = (const float*)d_in[7];
    float* out = (float*)d_out;

    const int H = in_sizes[3];          // 64
    const int D = in_sizes[2] / H;      // 128
    const int N = in_sizes[0] / D;      // 100000
    const int E = in_sizes[1] / 2;      // 1600000
    const int* row = ei;
    const int* col = ei + E;
    const int NBUK = (N + 511) >> 9;    // 196 buckets of 512 nodes
    const int CH   = (E + CHUNKS - 1) / CHUNKS;

    // Workspace carve-up (256B aligned slices)
    char* p = (char*)d_ws;
    auto carve = [&](size_t bytes) {
        char* r = p;
        p += (bytes + 255) & ~(size_t)255;
        return (void*)r;
    };
    int*            hist_g      = (int*)carve((size_t)CHUNKS * 256 * 4);
    int*            histOff     = (int*)carve((size_t)256 * CHUNKS * 4);
    int*            bucketTotal = (int*)carve((size_t)256 * 4);
    int*            bucketBase  = (int*)carve((size_t)256 * 4);
    unsigned*       ebuf        = (unsigned*)carve((size_t)E * 4);
    int*            csr_src     = (int*)carve((size_t)E * 4);
    int*            row_off     = (int*)carve((size_t)(N + 1) * 4);
    float*          dinv        = (float*)carve((size_t)N * 4);
    unsigned char*  bufXL8      = (unsigned char*)carve((size_t)N * 64);
    unsigned char*  bufXL2      = (unsigned char*)carve((size_t)N * 64);
    (void)ws_size;

    const int TB = 256;
    // 1. CSR build (bucketed counting sort; no global atomics)
    k_hist<<<CHUNKS, TB, 0, stream>>>(col, E, NBUK, CH, hist_g);
    k_colscan<<<NBUK, TB, 0, stream>>>(hist_g, NBUK, histOff, bucketTotal);
    k_scan_tot<<<1, TB, 0, stream>>>(bucketTotal, NBUK, E, N, bucketBase, row_off);
    k_scatter<<<CHUNKS, TB, 0, stream>>>(row, col, E, NBUK, CH, bucketBase, histOff, ebuf);
    k_bucket<<<NBUK, 512, 0, stream>>>(ebuf, bucketBase, bucketTotal, N,
                                       row_off, dinv, csr_src);

    int gemmGrid = (N + 63) / 64;       // 1563
    int aggGrid  = (N + 31) / 32;       // 3125 (8 nodes/wave x 4 waves)
    // 2. layer 1 GEMM: xl = fp8((x@W1)*dinv)
    k_gemm_mfma<128><<<gemmGrid, TB, 0, stream>>>(x, W1, dinv, bufXL8, N);
    // 3. fused layer-1 agg + gemm2: xl2 = fp8(dinv*(relu(dinv*Agg(xl)+b1)@W2))
    k_agg_g2<<<aggGrid, TB, 0, stream>>>(bufXL8, row_off, csr_src, dinv, b1, W2, bufXL2, N);
    // 4. layer-2 agg + FC + sigmoid
    k_agg_fc<<<aggGrid, TB, 0, stream>>>(bufXL2, row_off, csr_src, dinv, b2, Wfc, bfc, out, N);
}